// Round 4
// baseline (615.338 us; speedup 1.0000x reference)
//
#include <hip/hip_runtime.h>
#include <cstdint>

typedef _Float16 f16;
typedef __attribute__((ext_vector_type(8))) _Float16 f16x8;
typedef __attribute__((ext_vector_type(4))) _Float16 f16x4;
typedef __attribute__((ext_vector_type(2))) _Float16 f16x2;
typedef __attribute__((ext_vector_type(4))) float f32x4;
typedef __attribute__((ext_vector_type(16))) float f32x16;

#define D_MODEL 1024
#define T_SEQ   2048
#define NTOK    8192      // B*T
#define DFF     4096
#define DHEAD   64

struct alignas(16) H8 { f16 h[8]; };

// async global->LDS, 16B per lane. LDS dest must be wave-uniform base; HW adds lane*16.
__device__ __forceinline__ void load_lds16(const void* gp, void* lp) {
  __builtin_amdgcn_global_load_lds(
      (const __attribute__((address_space(1))) unsigned int*)(unsigned long long)(uintptr_t)gp,
      (__attribute__((address_space(3))) unsigned int*)(unsigned int)(uintptr_t)lp,
      16, 0, 0);
}

// raw phase barrier: no vmcnt(0) drain (unlike __syncthreads), but full
// compiler fence so LDS reads/writes can't migrate across phases.
__device__ __forceinline__ void phase_bar() {
  asm volatile("" ::: "memory");
  __builtin_amdgcn_sched_barrier(0);
  __builtin_amdgcn_s_barrier();
  __builtin_amdgcn_sched_barrier(0);
  asm volatile("" ::: "memory");
}

__device__ __forceinline__ void wait_vm2() {
  asm volatile("s_waitcnt vmcnt(2)" ::: "memory");
  __builtin_amdgcn_sched_barrier(0);
}
__device__ __forceinline__ void wait_vm0() {
  asm volatile("s_waitcnt vmcnt(0)" ::: "memory");
  __builtin_amdgcn_sched_barrier(0);
}

// out[c][r] = (f16) in[r][c];  in: [rows][cols] fp32 row-major. All dims %32==0.
__global__ __launch_bounds__(256) void transpose_pack(
    const float* __restrict__ in, f16* __restrict__ out,
    int rows, int cols, long long in_slice, long long out_slice)
{
  __shared__ float tile[32][33];
  const float* inp = in + (size_t)blockIdx.z * in_slice;
  f16* outp = out + (size_t)blockIdx.z * out_slice;
  int r0 = blockIdx.x * 32, c0 = blockIdx.y * 32;
  int tx = threadIdx.x & 31, ty = threadIdx.x >> 5;   // 32 x 8
  #pragma unroll
  for (int i = 0; i < 4; ++i)
    tile[ty + i*8][tx] = inp[(size_t)(r0 + ty + i*8)*cols + c0 + tx];
  __syncthreads();
  #pragma unroll
  for (int i = 0; i < 4; ++i)
    outp[(size_t)(c0 + ty + i*8)*rows + r0 + tx] = (f16)tile[tx][ty + i*8];
}

// row-wise layernorm over 1024; writes fp32 (residual path) + f16 (GEMM input)
__global__ __launch_bounds__(256) void ln_kernel(
    const float* __restrict__ x, const float* __restrict__ g, const float* __restrict__ b,
    float* __restrict__ outf, f16* __restrict__ outh)
{
  int row = blockIdx.x;
  const float* xr = x + (size_t)row * D_MODEL;
  int tid = threadIdx.x;
  float v[4];
  float s = 0.f;
  #pragma unroll
  for (int i = 0; i < 4; ++i) { v[i] = xr[tid + i*256]; s += v[i]; }
  #pragma unroll
  for (int off = 32; off > 0; off >>= 1) s += __shfl_down(s, off, 64);
  __shared__ float red1[4], red2[4];
  if ((tid & 63) == 0) red1[tid >> 6] = s;
  __syncthreads();
  float mean = (red1[0] + red1[1] + red1[2] + red1[3]) * (1.f / D_MODEL);
  float s2 = 0.f;
  #pragma unroll
  for (int i = 0; i < 4; ++i) { float d = v[i] - mean; s2 += d * d; }
  #pragma unroll
  for (int off = 32; off > 0; off >>= 1) s2 += __shfl_down(s2, off, 64);
  if ((tid & 63) == 0) red2[tid >> 6] = s2;
  __syncthreads();
  float var = (red2[0] + red2[1] + red2[2] + red2[3]) * (1.f / D_MODEL);
  float rstd = rsqrtf(var + 1e-5f);
  #pragma unroll
  for (int i = 0; i < 4; ++i) {
    int c = tid + i*256;
    float y = (v[i] - mean) * rstd * g[c] + b[c];
    outf[(size_t)row*D_MODEL + c] = y;
    outh[(size_t)row*D_MODEL + c] = (f16)y;
  }
}

// ---------------------------------------------------------------------------
// 256xBN phased GEMM (plain-HIP port of the 8-phase template, T2+T3+T4+T5):
//   C[M,N] = A[M,K] * BT[N,K]^T, f16 in, fp32 acc, 32x32x16 MFMA.
//   512 threads = 8 waves; BN=256 -> waves 2Mx4N (wave tile 128x64, MI=4);
//   BN=128 -> waves 4Mx2N (wave tile 64x64, MI=2).
//   Double-buffered LDS (BN=256: 128 KB, BN=128: 96 KB), 1 block/CU.
//   Per K-tile: 4 phases (BN=256) of {ds-read frags || stage 1 half-tile ->
//   barrier -> setprio(1) 8xMFMA setprio(0) -> barrier}; counted vmcnt(2)
//   ONCE per K-tile (never 0 in steady state) keeps the next tile's
//   global_load_lds in flight across barriers. A-frags cached across the two
//   ni-phases of an mi-pair; B-frags cached across mi-pairs -> phase 4 is
//   pure-MFMA, so the same-buffer A0 prefetch it issues is barrier-safe.
//   Bank swizzle (BK=64 rows = 128B = full bank wrap): LDS slot (row,pos)
//   holds global k-chunk (pos ^ (row&7)); reads use chunk = logical ^ (rl&7).
// MODE 0: scatter q/k/v (q scaled log2e/32) -> o0,o1,o2 [BH][T][64] f16
// MODE 1: outf = acc + bias[col] + resid[idx]            (proj, fp32)
// MODE 2: o0   = relu(acc + bias[col])                   (ffn1, f16, ld 4096)
// MODE 3: outf = acc + bias[col] + resid[idx]            (ffn2 -> d_out)
// ---------------------------------------------------------------------------

#define STAGE_H(gbase, h, ldst, k0)                                            \
  { _Pragma("unroll")                                                          \
    for (int j_ = 0; j_ < 2; ++j_) {                                           \
      int c_  = tid + j_*512;                                                  \
      int rr_ = c_ >> 3;                                                       \
      int cg_ = (c_ & 7) ^ (rr_ & 7);                                          \
      load_lds16((gbase) + (size_t)((h)*128 + rr_) * K + (k0) + cg_*8,         \
                 (ldst) + (h)*128*64 + (size_t)(c_ & ~63) * 8);                \
    } }

#define LDS_A(bsel, mp)                                                        \
  { _Pragma("unroll")                                                          \
    for (int i_ = 0; i_ < 2; ++i_)                                             \
      _Pragma("unroll")                                                        \
      for (int ks_ = 0; ks_ < 4; ++ks_)                                        \
        fa[i_][ks_] = *(const f16x8*)(&As[bsel][                               \
            (wm + ((mp)*2 + i_)*32 + rl)*64 + (((ks_*2 + hl) ^ sw)*8)]); }

#define LDS_B(bsel, ni, fb)                                                    \
  { _Pragma("unroll")                                                          \
    for (int ks_ = 0; ks_ < 4; ++ks_)                                          \
      fb[ks_] = *(const f16x8*)(&Bs[bsel][                                     \
          (wn + (ni)*32 + rl)*64 + (((ks_*2 + hl) ^ sw)*8)]); }

#define MFMA8(mp, ni, fb)                                                      \
  { __builtin_amdgcn_s_setprio(1);                                             \
    _Pragma("unroll")                                                          \
    for (int ks_ = 0; ks_ < 4; ++ks_) {                                        \
      acc[(mp)*2+0][ni] = __builtin_amdgcn_mfma_f32_32x32x16_f16(              \
          fa[0][ks_], fb[ks_], acc[(mp)*2+0][ni], 0, 0, 0);                    \
      acc[(mp)*2+1][ni] = __builtin_amdgcn_mfma_f32_32x32x16_f16(              \
          fa[1][ks_], fb[ks_], acc[(mp)*2+1][ni], 0, 0, 0);                    \
    }                                                                          \
    __builtin_amdgcn_s_setprio(0); }

template<int MODE, int BN>
__global__ __launch_bounds__(512, 2) void gemm8(
    const f16* __restrict__ A, const f16* __restrict__ BT, int K,
    const float* __restrict__ bias, const float* __restrict__ resid,
    float* __restrict__ outf, f16* __restrict__ o0, f16* __restrict__ o1, f16* __restrict__ o2)
{
  constexpr int BM  = 256;
  constexpr int NWN = BN / 64;            // waves along N (4 or 2)
  constexpr int MI  = (BM / (8 / NWN)) / 32;  // mi frags per wave (4 or 2)

  __shared__ __align__(16) f16 As[2][BM * 64];
  __shared__ __align__(16) f16 Bs[2][BN * 64];

  int tid  = threadIdx.x;
  int lane = tid & 63;
  int wave = tid >> 6;
  int rl = lane & 31, hl = lane >> 5;
  int sw = rl & 7;
  int wmi = wave / NWN, wni = wave % NWN;
  int wm = wmi * (MI * 32), wn = wni * 64;

  // bijective XCD swizzle (all current grids have nwg % 8 == 0; identity
  // fallback otherwise): each XCD sweeps contiguous block ids -> B-panel
  // stays resident in its L2.
  int gx  = gridDim.x;
  int nwg = gx * gridDim.y;
  int lin = blockIdx.x + gx * blockIdx.y;
  int sid = (nwg & 7) == 0 ? ((lin & 7) * (nwg >> 3) + (lin >> 3)) : lin;
  int bx  = sid % gx, by = sid / gx;

  size_t row0 = (size_t)bx * BM, col0 = (size_t)by * BN;
  const f16* a_base = A  + row0 * K;
  const f16* b_base = BT + col0 * K;
  int NT = K >> 6;

  f32x16 acc[MI][2];
  #pragma unroll
  for (int i = 0; i < MI; ++i)
    #pragma unroll
    for (int j = 0; j < 2; ++j)
      acc[i][j] = (f32x16)(0.f);

  f16x8 fa[2][4], fb0[4], fb1[4];

  if constexpr (BN == 256) {
    // ---- prologue: tile0 (A0,A1,B0,B1) + tile1 A0 in flight
    STAGE_H(a_base, 0, &As[0][0], 0);
    STAGE_H(a_base, 1, &As[0][0], 0);
    STAGE_H(b_base, 0, &Bs[0][0], 0);
    STAGE_H(b_base, 1, &Bs[0][0], 0);
    if (NT > 1) { STAGE_H(a_base, 0, &As[1][0], 64); wait_vm2(); }
    else        { wait_vm0(); }
    phase_bar();

    for (int t = 0; t < NT; ++t) {
      int cur = t & 1, nxt = cur ^ 1;
      int k1 = (t + 1) << 6, k2 = (t + 2) << 6;
      bool s1 = (t + 1) < NT, s2 = (t + 2) < NT;
      // ph1: (mi-pair 0, ni 0); prefetch (t+1).A1 -> other buffer
      LDS_A(cur, 0); LDS_B(cur, 0, fb0);
      if (s1) STAGE_H(a_base, 1, &As[nxt][0], k1);
      phase_bar();
      MFMA8(0, 0, fb0);
      phase_bar();
      // ph2: (0, 1); prefetch (t+1).B0
      LDS_B(cur, 1, fb1);
      if (s1) STAGE_H(b_base, 0, &Bs[nxt][0], k1);
      phase_bar();
      MFMA8(0, 1, fb1);
      phase_bar();
      // ph3: (1, 0) — fb0 cached; prefetch (t+1).B1
      LDS_A(cur, 1);
      if (s1) STAGE_H(b_base, 1, &Bs[nxt][0], k1);
      phase_bar();
      MFMA8(1, 0, fb0);
      phase_bar();
      // ph4: (1, 1) — pure MFMA; prefetch (t+2).A0 into the buffer this
      // iteration just finished reading (all A reads done by end of ph3).
      if (s2) STAGE_H(a_base, 0, &As[cur][0], k2);
      phase_bar();
      MFMA8(1, 1, fb1);
      if (s2) wait_vm2(); else wait_vm0();   // (t+1) fully landed; (t+2).A0 in flight
      phase_bar();
    }
  } else {
    // ---- BN=128: MI=2, 2 phases per K-tile, 2 K-tiles per iteration.
    // buffers fixed by tile parity. B has a single 128-row half.
    STAGE_H(a_base, 0, &As[0][0], 0);
    STAGE_H(a_base, 1, &As[0][0], 0);
    STAGE_H(b_base, 0, &Bs[0][0], 0);
    if (NT > 1) { STAGE_H(a_base, 0, &As[1][0], 64); wait_vm2(); }
    else        { wait_vm0(); }
    phase_bar();

    for (int t = 0; t < NT; t += 2) {
      int k1 = (t + 1) << 6, k2 = (t + 2) << 6, k3 = (t + 3) << 6;
      bool s1 = (t + 1) < NT, s2 = (t + 2) < NT, s3 = (t + 3) < NT;
      // ph1: tile t (buf0), ni0; prefetch (t+1).A1 + (t+1).B -> buf1
      LDS_A(0, 0); LDS_B(0, 0, fb0);
      if (s1) { STAGE_H(a_base, 1, &As[1][0], k1); STAGE_H(b_base, 0, &Bs[1][0], k1); }
      phase_bar();
      MFMA8(0, 0, fb0);
      phase_bar();
      // ph2: tile t, ni1; prefetch (t+2).A0 -> buf0 (A reads done at ph1)
      LDS_B(0, 1, fb1);
      if (s2) STAGE_H(a_base, 0, &As[0][0], k2);
      phase_bar();
      MFMA8(0, 1, fb1);
      if (s2) wait_vm2(); else wait_vm0();   // (t+1) landed; (t+2).A0 in flight
      phase_bar();
      if (!s1) break;
      // ph3: tile t+1 (buf1), ni0; prefetch (t+2).A1 + (t+2).B -> buf0
      LDS_A(1, 0); LDS_B(1, 0, fb0);
      if (s2) { STAGE_H(a_base, 1, &As[0][0], k2); STAGE_H(b_base, 0, &Bs[0][0], k2); }
      phase_bar();
      MFMA8(0, 0, fb0);
      phase_bar();
      // ph4: tile t+1, ni1; prefetch (t+3).A0 -> buf1
      LDS_B(1, 1, fb1);
      if (s3) STAGE_H(a_base, 0, &As[1][0], k3);
      phase_bar();
      MFMA8(0, 1, fb1);
      if (s3) wait_vm2(); else wait_vm0();   // (t+2) landed; (t+3).A0 in flight
      phase_bar();
    }
  }

  // epilogue: 32x32 C layout (m74/m101): col=lane&31, row=(reg&3)+8*(reg>>2)+4*(lane>>5)
  int rb = hl * 4;
  #pragma unroll
  for (int mi = 0; mi < MI; ++mi) {
    #pragma unroll
    for (int ni = 0; ni < 2; ++ni) {
      #pragma unroll
      for (int r = 0; r < 16; ++r) {
        size_t grow = row0 + wm + mi*32 + rb + (r & 3) + 8 * (r >> 2);
        size_t gcol = col0 + wn + ni*32 + rl;
        float v = acc[mi][ni][r];
        if constexpr (MODE == 0) {
          int sel = (int)(gcol >> 10);
          int hh  = ((int)gcol >> 6) & 15;
          int dd  = (int)gcol & 63;
          f16* dst = (sel == 0) ? o0 : ((sel == 1) ? o1 : o2);
          if (sel == 0) v *= 0.045084229f;   // (1/32) * log2(e): exp2-domain scores
          size_t bh = (grow >> 11) * 16 + hh;
          dst[(bh * T_SEQ + (grow & 2047)) * DHEAD + dd] = (f16)v;
        } else if constexpr (MODE == 1 || MODE == 3) {
          size_t idx = grow * D_MODEL + gcol;
          outf[idx] = v + bias[gcol] + resid[idx];
        } else {  // MODE 2
          float t = v + bias[gcol];
          o0[grow * (size_t)DFF + gcol] = (f16)(t > 0.f ? t : 0.f);
        }
      }
    }
  }
}

// MFMA flash attention, S^T formulation + fixed-max softmax.
// One q-tile (qi) per block: grid (16, 64), qi = 15 - bx so heavy blocks
// dispatch first and light blocks backfill. 1024 blocks; LDS 36.9KB allows
// 4 blocks/CU. NO launch_bounds wave cap: round-3's (256,4) squeezed VGPR to
// 64 and spilled the accumulators (+49MB scratch WRITE_SIZE, 105->137us).
// Natural allocation (~100 VGPR) still supports 4 waves/SIMD.
// T14 async-stage: next tile's K/V are prefetched into registers during the
// current tile's compute; LDS writes happen after the consume-barrier.
// Scores arrive already in log2 domain (q scaled by log2e/32 at QKV epilogue),
// softmax max fixed at 0 (scores have std ~0.36 in log2 domain -- exp2 cannot
// overflow; softmax is shift-invariant so exact).
// S^T = K*Q^T puts each q-row's keys in ONE lane's registers: no per-tile
// shuffles; P^T lane data is key-contiguous -> b64 LDS writes, b128 A-frag reads.
__global__ __launch_bounds__(256) void attn_mfma(
    const f16* __restrict__ qb, const f16* __restrict__ kb,
    const f16* __restrict__ vb, f16* __restrict__ attnb)
{
  constexpr int KT  = 64;
  constexpr int LDK = 72;                        // padded f16 stride (K, Vt, Pt)
  __shared__ __align__(16) f16 Kl[KT * LDK];     // [key][d]
  __shared__ __align__(16) f16 Vt[DHEAD * LDK];  // [d][key]
  __shared__ __align__(16) f16 Pt[4 * 32 * LDK]; // per-wave [q 0..31][key]

  int tid  = threadIdx.x;
  int lane = tid & 63, wave = tid >> 6;
  int n    = lane & 15, quad = lane >> 4;
  int quad4 = quad * 4;
  int bh   = blockIdx.y;

  const f16* qg = qb + (size_t)bh * T_SEQ * DHEAD;
  const f16* kg = kb + (size_t)bh * T_SEQ * DHEAD;
  const f16* vg = vb + (size_t)bh * T_SEQ * DHEAD;
  f16* Ptw = Pt + wave * 32 * LDK;
  size_t orow = (size_t)(bh >> 4) * T_SEQ;
  int hcol = (bh & 15) * DHEAD;

  int qi = 15 - (int)blockIdx.x;                 // heavy first in dispatch order
  int qw = qi * 128 + wave * 32;                 // this wave's first q row

  // staging geometry (constant per thread)
  int skey0 = tid >> 3,  sdq = tid & 7;          // K halves: keys skey0, skey0+32
  int kp = tid & 31, dblk = tid >> 5;            // V: keys 2kp,2kp+1; d = dblk*8+e

  // Q fragments (B-operand): lane n holds Q[q=qw+ni*16+n][d=quad*8+j]
  f16x8 qfrag[2][2];
  #pragma unroll
  for (int ni = 0; ni < 2; ++ni)
    #pragma unroll
    for (int kj = 0; kj < 2; ++kj)
      qfrag[ni][kj] = *(const f16x8*)(qg + (size_t)(qw + ni*16 + n)*DHEAD + kj*32 + quad*8);

  f32x4 o[2][4];
  #pragma unroll
  for (int mb = 0; mb < 2; ++mb)
    #pragma unroll
    for (int di = 0; di < 4; ++di) o[mb][di] = f32x4{0.f,0.f,0.f,0.f};
  float lsum[2] = {0.f, 0.f};

  int ntiles = 2 * qi + 2;

  // prefetch tile 0 into registers
  uint4 kpre0, kpre1;
  H8 vpa, vpb;
  {
    kpre0 = *(const uint4*)(kg + (size_t)skey0 * DHEAD + sdq * 8);
    kpre1 = *(const uint4*)(kg + (size_t)(skey0 + 32) * DHEAD + sdq * 8);
    const f16* v0 = vg + (size_t)(2*kp) * DHEAD + dblk * 8;
    vpa = *(const H8*)v0;
    vpb = *(const H8*)(v0 + DHEAD);
  }

  for (int kt = 0; kt < ntiles; ++kt) {
    int kt0 = kt * KT;
    __syncthreads();                             // prev tile fully consumed
    // write prefetched K [64 keys][64 d]
    *(uint4*)(Kl + skey0 * LDK + sdq * 8) = kpre0;
    *(uint4*)(Kl + (skey0 + 32) * LDK + sdq * 8) = kpre1;
    // write prefetched V transposed, packed f16x2 (adjacent keys share a dword)
    #pragma unroll
    for (int e = 0; e < 8; ++e) {
      f16x2 pk2; pk2[0] = vpa.h[e]; pk2[1] = vpb.h[e];
      *(f16x2*)(Vt + (dblk*8 + e) * LDK + 2*kp) = pk2;
    }
    // issue next tile's loads; latency hides under this tile's compute
    if (kt + 1 < ntiles) {
      int nt0 = kt0 + KT;
      kpre0 = *(const uint4*)(kg + (size_t)(nt0 + skey0) * DHEAD + sdq * 8);
      kpre1 = *(const uint4*)(kg + (size_t)(nt0 + skey0 + 32) * DHEAD + sdq * 8);
      const f16* v0 = vg + (size_t)(nt0 + 2*kp) * DHEAD + dblk * 8;
      vpa = *(const H8*)v0;
      vpb = *(const H8*)(v0 + DHEAD);
    }
    __syncthreads();

    if (kt0 > qw + 31) continue;                 // fully masked for this wave
    bool need_mask = (kt0 + KT - 1) > qw;        // diagonal tile

    // S^T = K Q^T : [64 key][32 q]; lane holds (key=mi*16+quad4+r, q=ni*16+n)
    f32x4 st[4][2];
    #pragma unroll
    for (int mi = 0; mi < 4; ++mi)
      #pragma unroll
      for (int ni = 0; ni < 2; ++ni) st[mi][ni] = f32x4{0.f,0.f,0.f,0.f};
    #pragma unroll
    for (int kj = 0; kj < 2; ++kj) {
      #pragma unroll
      for (int mi = 0; mi < 4; ++mi) {
        f16x8 kf = *(const f16x8*)(Kl + (mi*16 + n) * LDK + kj*32 + quad*8);
        #pragma unroll
        for (int ni = 0; ni < 2; ++ni)
          st[mi][ni] = __builtin_amdgcn_mfma_f32_16x16x32_f16(kf, qfrag[ni][kj], st[mi][ni], 0, 0, 0);
      }
    }

    // p = exp2(s'); per-lane row-sum accumulate; P^T -> LDS (b64, key-contig)
    #pragma unroll
    for (int ni = 0; ni < 2; ++ni) {
      #pragma unroll
      for (int mi = 0; mi < 4; ++mi) {
        f16x4 pk;
        #pragma unroll
        for (int r = 0; r < 4; ++r) {
          float sv = st[mi][ni][r];
          if (need_mask) {
            int key = kt0 + mi*16 + quad4 + r;
            int qq  = qw  + ni*16 + n;
            if (key > qq) sv = -1e30f;
          }
          float p = __builtin_amdgcn_exp2f(sv);
          lsum[ni] += p;
          pk[r] = (f16)p;
        }
        *(f16x4*)(Ptw + (ni*16 + n) * LDK + mi*16 + quad4) = pk;
      }
    }

    // O += P V : A-frag = Pt rows (b128, same-wave RAW), B-frag = Vt rows
    #pragma unroll
    for (int kj = 0; kj < 2; ++kj) {
      f16x8 pf[2];
      #pragma unroll
      for (int mb = 0; mb < 2; ++mb)
        pf[mb] = *(const f16x8*)(Ptw + (mb*16 + n) * LDK + kj*32 + quad*8);
      #pragma unroll
      for (int di = 0; di < 4; ++di) {
        f16x8 vf = *(const f16x8*)(Vt + (di*16 + n) * LDK + kj*32 + quad*8);
        #pragma unroll
        for (int mb = 0; mb < 2; ++mb)
          o[mb][di] = __builtin_amdgcn_mfma_f32_16x16x32_f16(pf[mb], vf, o[mb][di], 0, 0, 0);
      }
    }
  }

  // finish l: quads hold disjoint key-subsets of each q-row -> 2 shuffles
  #pragma unroll
  for (int ni = 0; ni < 2; ++ni) {
    lsum[ni] += __shfl_xor(lsum[ni], 16, 64);
    lsum[ni] += __shfl_xor(lsum[ni], 32, 64);
  }
  // epilogue: O C-layout lane holds (q=mb*16+quad4+r, d=di*16+n)
  #pragma unroll
  for (int mb = 0; mb < 2; ++mb) {
    #pragma unroll
    for (int r = 0; r < 4; ++r) {
      float lv  = __shfl(lsum[mb], quad4 + r, 64);   // lane n'=quad4+r holds q's sum
      float inv = 1.f / lv;
      int t = qw + mb*16 + quad4 + r;
      #pragma unroll
      for (int di = 0; di < 4; ++di)
        attnb[(orow + t) * D_MODEL + hcol + di*16 + n] = (f16)(o[mb][di][r] * inv);
    }
  }
}

extern "C" void kernel_launch(void* const* d_in, const int* in_sizes, int n_in,
                              void* d_out, int out_size, void* d_ws, size_t ws_size,
                              hipStream_t stream)
{
  const float* x     = (const float*)d_in[0];
  const float* Wq    = (const float*)d_in[1];
  const float* Wk    = (const float*)d_in[2];
  const float* Wv    = (const float*)d_in[3];
  const float* Wproj = (const float*)d_in[4];
  const float* bproj = (const float*)d_in[5];
  const float* W1    = (const float*)d_in[6];
  const float* b1    = (const float*)d_in[7];
  const float* W2    = (const float*)d_in[8];
  const float* b2    = (const float*)d_in[9];
  const float* g1    = (const float*)d_in[10];
  const float* bt1   = (const float*)d_in[11];
  const float* g2    = (const float*)d_in[12];
  const float* bt2   = (const float*)d_in[13];
  float* out = (float*)d_out;
  (void)in_sizes; (void)n_in; (void)out_size; (void)ws_size;

  char* ws = (char*)d_ws;
  const size_t SZ_H16 = (size_t)NTOK * D_MODEL * 2;  // 16.78 MB
  const size_t SZ_F32 = (size_t)NTOK * D_MODEL * 4;  // 33.55 MB
  f16*   qb      = (f16*)(ws + 0);
  f16*   kb      = (f16*)(ws + 1 * SZ_H16);
  f16*   vb      = (f16*)(ws + 2 * SZ_H16);
  f16*   attnb   = (f16*)(ws + 3 * SZ_H16);
  f16*   hbuf    = (f16*)(ws + 0);                   // reuses q/k/v/attn after proj (67.1MB)
  float* x1f     = (float*)(ws + 4 * SZ_H16);        // becomes x2 in-place at proj
  f16*   x1h     = (f16*)(ws + 4 * SZ_H16 + SZ_F32);
  float* x3f     = (float*)(ws + 5 * SZ_H16 + SZ_F32);
  f16*   x3h     = (f16*)(ws + 5 * SZ_H16 + 2 * SZ_F32);
  char*  wb      = ws + 6 * SZ_H16 + 2 * SZ_F32;
  f16*   Wqkv_t  = (f16*)(wb);                                       // [3072][1024]
  f16*   Wproj_t = (f16*)(wb + (size_t)3072*1024*2);                 // [1024][1024]
  f16*   W1_t    = (f16*)(wb + (size_t)(3072+1024)*1024*2);          // [4096][1024]
  f16*   W2_t    = (f16*)(wb + (size_t)(3072+1024+4096)*1024*2);     // [1024][4096]

  dim3 blk(256), blk5(512);
  // ---- pack weights to f16 B^T layouts
  transpose_pack<<<dim3(32, 2, 16), blk, 0, stream>>>(Wq, Wqkv_t,                 1024, 64,  65536, 65536);
  transpose_pack<<<dim3(32, 2, 16), blk, 0, stream>>>(Wk, Wqkv_t + 1024*1024,     1024, 64,  65536, 65536);
  transpose_pack<<<dim3(32, 2, 16), blk, 0, stream>>>(Wv, Wqkv_t + 2*1024*1024,   1024, 64,  65536, 65536);
  transpose_pack<<<dim3(32, 32, 1), blk, 0, stream>>>(Wproj, Wproj_t, 1024, 1024, 0, 0);
  transpose_pack<<<dim3(32, 128, 1), blk, 0, stream>>>(W1, W1_t, 1024, 4096, 0, 0);
  transpose_pack<<<dim3(128, 32, 1), blk, 0, stream>>>(W2, W2_t, 4096, 1024, 0, 0);
  // ---- ln1
  ln_kernel<<<NTOK, blk, 0, stream>>>(x, g1, bt1, x1f, x1h);
  // ---- fused QKV gemm [8192,1024] x [1024,3072]   (BN=128: 768 wg = 3 full rounds)
  gemm8<0,128><<<dim3(32, 24), blk5, 0, stream>>>(x1h, Wqkv_t, 1024, nullptr, nullptr, nullptr, qb, kb, vb);
  // ---- attention (MFMA flash, one q-tile per block, heavy-first)
  attn_mfma<<<dim3(16, 64), blk, 0, stream>>>(qb, kb, vb, attnb);
  // ---- proj + bias + residual(x1) -> x2 (in place over x1f)  (256 wg = 1 round)
  gemm8<1,128><<<dim3(32, 8), blk5, 0, stream>>>(attnb, Wproj_t, 1024, bproj, x1f, x1f, nullptr, nullptr, nullptr);
  // ---- ln2
  ln_kernel<<<NTOK, blk, 0, stream>>>(x1f, g2, bt2, x3f, x3h);
  // ---- ffn1: relu(x3 @ W1 + b1)   (BN=256: 512 wg = 2 full rounds)
  gemm8<2,256><<<dim3(32, 16), blk5, 0, stream>>>(x3h, W1_t, 1024, b1, nullptr, nullptr, hbuf, nullptr, nullptr);
  // ---- ffn2: x3 + h @ W2 + b2 -> out   (256 wg = 1 round)
  gemm8<3,128><<<dim3(32, 8), blk5, 0, stream>>>(hbuf, W2_t, 4096, b2, x3f, out, nullptr, nullptr, nullptr);
}

// Round 6
// 514.864 us; speedup vs baseline: 1.1951x; 1.1951x over previous
//
#include <hip/hip_runtime.h>
#include <cstdint>

typedef _Float16 f16;
typedef __attribute__((ext_vector_type(8))) _Float16 f16x8;
typedef __attribute__((ext_vector_type(4))) _Float16 f16x4;
typedef __attribute__((ext_vector_type(2))) _Float16 f16x2;
typedef __attribute__((ext_vector_type(4))) float f32x4;
typedef __attribute__((ext_vector_type(16))) float f32x16;

#define D_MODEL 1024
#define T_SEQ   2048
#define NTOK    8192      // B*T
#define DFF     4096
#define DHEAD   64

struct alignas(16) H8 { f16 h[8]; };

// async global->LDS, 16B per lane. LDS dest must be wave-uniform base; HW adds lane*16.
__device__ __forceinline__ void load_lds16(const void* gp, void* lp) {
  __builtin_amdgcn_global_load_lds(
      (const __attribute__((address_space(1))) unsigned int*)(unsigned long long)(uintptr_t)gp,
      (__attribute__((address_space(3))) unsigned int*)(unsigned int)(uintptr_t)lp,
      16, 0, 0);
}

// raw phase barrier: no vmcnt(0) drain (unlike __syncthreads), but full
// compiler fence so LDS reads/writes can't migrate across phases.
__device__ __forceinline__ void phase_bar() {
  asm volatile("" ::: "memory");
  __builtin_amdgcn_sched_barrier(0);
  __builtin_amdgcn_s_barrier();
  __builtin_amdgcn_sched_barrier(0);
  asm volatile("" ::: "memory");
}

__device__ __forceinline__ void wait_vm2() {
  asm volatile("s_waitcnt vmcnt(2)" ::: "memory");
  __builtin_amdgcn_sched_barrier(0);
}
__device__ __forceinline__ void wait_vm0() {
  asm volatile("s_waitcnt vmcnt(0)" ::: "memory");
  __builtin_amdgcn_sched_barrier(0);
}

// ---------------------------------------------------------------------------
// All six weight transposes fused into ONE kernel (was 6 launches):
// out[c][r] = (f16) in[r][c]. 12288 blocks x one 32x32 tile each.
// ranges: [0,3072) Wq/Wk/Wv (16 slices of [1024][64] each)
//         [3072,4096) Wproj [1024][1024]
//         [4096,8192) W1 [1024][4096]
//         [8192,12288) W2 [4096][1024]
// ---------------------------------------------------------------------------
__global__ __launch_bounds__(256) void transpose_all(
    const float* __restrict__ Wq, const float* __restrict__ Wk,
    const float* __restrict__ Wv, const float* __restrict__ Wproj,
    const float* __restrict__ W1, const float* __restrict__ W2,
    f16* __restrict__ Wqkv_t, f16* __restrict__ Wproj_t,
    f16* __restrict__ W1_t, f16* __restrict__ W2_t)
{
  __shared__ float tile[32][33];
  int b = blockIdx.x;
  const float* in; f16* out; int rows, cols, r0, c0;
  if (b < 3072) {
    int j = b >> 10;                       // 0,1,2 -> q,k,v
    int local = b & 1023;
    int slice = local >> 6;                // 64 tiles per [1024][64] slice
    int tl = local & 63;
    in  = (j == 0 ? Wq : (j == 1 ? Wk : Wv)) + (size_t)slice * 65536;
    out = Wqkv_t + (size_t)j * 1024 * 1024 + (size_t)slice * 65536;
    rows = 1024; cols = 64;
    r0 = (tl & 31) * 32; c0 = (tl >> 5) * 32;
  } else if (b < 4096) {
    int tl = b - 3072;
    in = Wproj; out = Wproj_t; rows = 1024; cols = 1024;
    r0 = (tl & 31) * 32; c0 = (tl >> 5) * 32;
  } else if (b < 8192) {
    int tl = b - 4096;
    in = W1; out = W1_t; rows = 1024; cols = 4096;
    r0 = (tl & 31) * 32; c0 = (tl >> 5) * 32;
  } else {
    int tl = b - 8192;
    in = W2; out = W2_t; rows = 4096; cols = 1024;
    r0 = (tl & 127) * 32; c0 = (tl >> 7) * 32;
  }
  int tx = threadIdx.x & 31, ty = threadIdx.x >> 5;   // 32 x 8
  #pragma unroll
  for (int i = 0; i < 4; ++i)
    tile[ty + i*8][tx] = in[(size_t)(r0 + ty + i*8)*cols + c0 + tx];
  __syncthreads();
  #pragma unroll
  for (int i = 0; i < 4; ++i)
    out[(size_t)(c0 + ty + i*8)*rows + r0 + tx] = (f16)tile[tx][ty + i*8];
}

// row-wise layernorm over 1024; writes fp32 (residual path) + f16 (GEMM input)
__global__ __launch_bounds__(256) void ln_kernel(
    const float* __restrict__ x, const float* __restrict__ g, const float* __restrict__ b,
    float* __restrict__ outf, f16* __restrict__ outh)
{
  int row = blockIdx.x;
  const float* xr = x + (size_t)row * D_MODEL;
  int tid = threadIdx.x;
  float v[4];
  float s = 0.f;
  #pragma unroll
  for (int i = 0; i < 4; ++i) { v[i] = xr[tid + i*256]; s += v[i]; }
  #pragma unroll
  for (int off = 32; off > 0; off >>= 1) s += __shfl_down(s, off, 64);
  __shared__ float red1[4], red2[4];
  if ((tid & 63) == 0) red1[tid >> 6] = s;
  __syncthreads();
  float mean = (red1[0] + red1[1] + red1[2] + red1[3]) * (1.f / D_MODEL);
  float s2 = 0.f;
  #pragma unroll
  for (int i = 0; i < 4; ++i) { float d = v[i] - mean; s2 += d * d; }
  #pragma unroll
  for (int off = 32; off > 0; off >>= 1) s2 += __shfl_down(s2, off, 64);
  if ((tid & 63) == 0) red2[tid >> 6] = s2;
  __syncthreads();
  float var = (red2[0] + red2[1] + red2[2] + red2[3]) * (1.f / D_MODEL);
  float rstd = rsqrtf(var + 1e-5f);
  #pragma unroll
  for (int i = 0; i < 4; ++i) {
    int c = tid + i*256;
    float y = (v[i] - mean) * rstd * g[c] + b[c];
    outf[(size_t)row*D_MODEL + c] = y;
    outh[(size_t)row*D_MODEL + c] = (f16)y;
  }
}

// ---------------------------------------------------------------------------
// 256xBN phased GEMM (plain-HIP port of the 8-phase template, T2+T3+T4+T5):
//   C[M,N] = A[M,K] * BT[N,K]^T, f16 in, fp32 acc, 32x32x16 MFMA.
//   512 threads = 8 waves; BN=256 -> waves 2Mx4N (wave tile 128x64, MI=4);
//   BN=128 -> waves 4Mx2N (wave tile 64x64, MI=2).
//   Double-buffered LDS (BN=256: 128 KB, BN=128: 96 KB), 1 block/CU.
//   Per K-tile: 4 phases (BN=256) of {ds-read frags || stage 1 half-tile ->
//   barrier -> setprio(1) 8xMFMA setprio(0) -> barrier}; counted vmcnt(2)
//   ONCE per K-tile (never 0 in steady state) keeps the next tile's
//   global_load_lds in flight across barriers. A-frags cached across the two
//   ni-phases of an mi-pair; B-frags cached across mi-pairs -> phase 4 is
//   pure-MFMA, so the same-buffer A0 prefetch it issues is barrier-safe.
//   Bank swizzle (BK=64 rows = 128B = full bank wrap): LDS slot (row,pos)
//   holds global k-chunk (pos ^ (row&7)); reads use chunk = logical ^ (rl&7).
// MODE 0: scatter q/k/v (q scaled log2e/32) -> o0,o1,o2 [BH][T][64] f16
// MODE 1: outf = acc + bias[col] + resid[idx]            (proj, fp32)
// MODE 2: o0   = relu(acc + bias[col])                   (ffn1, f16, ld 4096)
// MODE 3: outf = acc + bias[col] + resid[idx]            (ffn2 -> d_out)
// ---------------------------------------------------------------------------

#define STAGE_H(gbase, h, ldst, k0)                                            \
  { _Pragma("unroll")                                                          \
    for (int j_ = 0; j_ < 2; ++j_) {                                           \
      int c_  = tid + j_*512;                                                  \
      int rr_ = c_ >> 3;                                                       \
      int cg_ = (c_ & 7) ^ (rr_ & 7);                                          \
      load_lds16((gbase) + (size_t)((h)*128 + rr_) * K + (k0) + cg_*8,         \
                 (ldst) + (h)*128*64 + (size_t)(c_ & ~63) * 8);                \
    } }

#define LDS_A(bsel, mp)                                                        \
  { _Pragma("unroll")                                                          \
    for (int i_ = 0; i_ < 2; ++i_)                                             \
      _Pragma("unroll")                                                        \
      for (int ks_ = 0; ks_ < 4; ++ks_)                                        \
        fa[i_][ks_] = *(const f16x8*)(&As[bsel][                               \
            (wm + ((mp)*2 + i_)*32 + rl)*64 + (((ks_*2 + hl) ^ sw)*8)]); }

#define LDS_B(bsel, ni, fb)                                                    \
  { _Pragma("unroll")                                                          \
    for (int ks_ = 0; ks_ < 4; ++ks_)                                          \
      fb[ks_] = *(const f16x8*)(&Bs[bsel][                                     \
          (wn + (ni)*32 + rl)*64 + (((ks_*2 + hl) ^ sw)*8)]); }

#define MFMA8(mp, ni, fb)                                                      \
  { __builtin_amdgcn_s_setprio(1);                                             \
    _Pragma("unroll")                                                          \
    for (int ks_ = 0; ks_ < 4; ++ks_) {                                        \
      acc[(mp)*2+0][ni] = __builtin_amdgcn_mfma_f32_32x32x16_f16(              \
          fa[0][ks_], fb[ks_], acc[(mp)*2+0][ni], 0, 0, 0);                    \
      acc[(mp)*2+1][ni] = __builtin_amdgcn_mfma_f32_32x32x16_f16(              \
          fa[1][ks_], fb[ks_], acc[(mp)*2+1][ni], 0, 0, 0);                    \
    }                                                                          \
    __builtin_amdgcn_s_setprio(0); }

template<int MODE, int BN>
__global__ __launch_bounds__(512, 2) void gemm8(
    const f16* __restrict__ A, const f16* __restrict__ BT, int K,
    const float* __restrict__ bias, const float* __restrict__ resid,
    float* __restrict__ outf, f16* __restrict__ o0, f16* __restrict__ o1, f16* __restrict__ o2)
{
  constexpr int BM  = 256;
  constexpr int NWN = BN / 64;            // waves along N (4 or 2)
  constexpr int MI  = (BM / (8 / NWN)) / 32;  // mi frags per wave (4 or 2)

  __shared__ __align__(16) f16 As[2][BM * 64];
  __shared__ __align__(16) f16 Bs[2][BN * 64];

  int tid  = threadIdx.x;
  int lane = tid & 63;
  int wave = tid >> 6;
  int rl = lane & 31, hl = lane >> 5;
  int sw = rl & 7;
  int wmi = wave / NWN, wni = wave % NWN;
  int wm = wmi * (MI * 32), wn = wni * 64;

  // bijective XCD swizzle (all current grids have nwg % 8 == 0; identity
  // fallback otherwise): each XCD sweeps contiguous block ids -> B-panel
  // stays resident in its L2.
  int gx  = gridDim.x;
  int nwg = gx * gridDim.y;
  int lin = blockIdx.x + gx * blockIdx.y;
  int sid = (nwg & 7) == 0 ? ((lin & 7) * (nwg >> 3) + (lin >> 3)) : lin;
  int bx  = sid % gx, by = sid / gx;

  size_t row0 = (size_t)bx * BM, col0 = (size_t)by * BN;
  const f16* a_base = A  + row0 * K;
  const f16* b_base = BT + col0 * K;
  int NT = K >> 6;

  f32x16 acc[MI][2];
  #pragma unroll
  for (int i = 0; i < MI; ++i)
    #pragma unroll
    for (int j = 0; j < 2; ++j)
      acc[i][j] = (f32x16)(0.f);

  f16x8 fa[2][4], fb0[4], fb1[4];

  if constexpr (BN == 256) {
    // ---- prologue: tile0 (A0,A1,B0,B1) + tile1 A0 in flight
    STAGE_H(a_base, 0, &As[0][0], 0);
    STAGE_H(a_base, 1, &As[0][0], 0);
    STAGE_H(b_base, 0, &Bs[0][0], 0);
    STAGE_H(b_base, 1, &Bs[0][0], 0);
    if (NT > 1) { STAGE_H(a_base, 0, &As[1][0], 64); wait_vm2(); }
    else        { wait_vm0(); }
    phase_bar();

    for (int t = 0; t < NT; ++t) {
      int cur = t & 1, nxt = cur ^ 1;
      int k1 = (t + 1) << 6, k2 = (t + 2) << 6;
      bool s1 = (t + 1) < NT, s2 = (t + 2) < NT;
      // ph1: (mi-pair 0, ni 0); prefetch (t+1).A1 -> other buffer
      LDS_A(cur, 0); LDS_B(cur, 0, fb0);
      if (s1) STAGE_H(a_base, 1, &As[nxt][0], k1);
      phase_bar();
      MFMA8(0, 0, fb0);
      phase_bar();
      // ph2: (0, 1); prefetch (t+1).B0
      LDS_B(cur, 1, fb1);
      if (s1) STAGE_H(b_base, 0, &Bs[nxt][0], k1);
      phase_bar();
      MFMA8(0, 1, fb1);
      phase_bar();
      // ph3: (1, 0) — fb0 cached; prefetch (t+1).B1
      LDS_A(cur, 1);
      if (s1) STAGE_H(b_base, 1, &Bs[nxt][0], k1);
      phase_bar();
      MFMA8(1, 0, fb0);
      phase_bar();
      // ph4: (1, 1) — pure MFMA; prefetch (t+2).A0 into the buffer this
      // iteration just finished reading (all A reads done by end of ph3).
      if (s2) STAGE_H(a_base, 0, &As[cur][0], k2);
      phase_bar();
      MFMA8(1, 1, fb1);
      if (s2) wait_vm2(); else wait_vm0();   // (t+1) fully landed; (t+2).A0 in flight
      phase_bar();
    }
  } else {
    // ---- BN=128: MI=2, 2 phases per K-tile, 2 K-tiles per iteration.
    // buffers fixed by tile parity. B has a single 128-row half.
    STAGE_H(a_base, 0, &As[0][0], 0);
    STAGE_H(a_base, 1, &As[0][0], 0);
    STAGE_H(b_base, 0, &Bs[0][0], 0);
    if (NT > 1) { STAGE_H(a_base, 0, &As[1][0], 64); wait_vm2(); }
    else        { wait_vm0(); }
    phase_bar();

    for (int t = 0; t < NT; t += 2) {
      int k1 = (t + 1) << 6, k2 = (t + 2) << 6, k3 = (t + 3) << 6;
      bool s1 = (t + 1) < NT, s2 = (t + 2) < NT, s3 = (t + 3) < NT;
      // ph1: tile t (buf0), ni0; prefetch (t+1).A1 + (t+1).B -> buf1
      LDS_A(0, 0); LDS_B(0, 0, fb0);
      if (s1) { STAGE_H(a_base, 1, &As[1][0], k1); STAGE_H(b_base, 0, &Bs[1][0], k1); }
      phase_bar();
      MFMA8(0, 0, fb0);
      phase_bar();
      // ph2: tile t, ni1; prefetch (t+2).A0 -> buf0 (A reads done at ph1)
      LDS_B(0, 1, fb1);
      if (s2) STAGE_H(a_base, 0, &As[0][0], k2);
      phase_bar();
      MFMA8(0, 1, fb1);
      if (s2) wait_vm2(); else wait_vm0();   // (t+1) landed; (t+2).A0 in flight
      phase_bar();
      if (!s1) break;
      // ph3: tile t+1 (buf1), ni0; prefetch (t+2).A1 + (t+2).B -> buf0
      LDS_A(1, 0); LDS_B(1, 0, fb0);
      if (s2) { STAGE_H(a_base, 1, &As[0][0], k2); STAGE_H(b_base, 0, &Bs[0][0], k2); }
      phase_bar();
      MFMA8(0, 0, fb0);
      phase_bar();
      // ph4: tile t+1, ni1; prefetch (t+3).A0 -> buf1
      LDS_B(1, 1, fb1);
      if (s3) STAGE_H(a_base, 0, &As[1][0], k3);
      phase_bar();
      MFMA8(0, 1, fb1);
      if (s3) wait_vm2(); else wait_vm0();   // (t+2) landed; (t+3).A0 in flight
      phase_bar();
    }
  }

  // epilogue: 32x32 C layout (m74/m101): col=lane&31, row=(reg&3)+8*(reg>>2)+4*(lane>>5)
  int rb = hl * 4;
  #pragma unroll
  for (int mi = 0; mi < MI; ++mi) {
    #pragma unroll
    for (int ni = 0; ni < 2; ++ni) {
      #pragma unroll
      for (int r = 0; r < 16; ++r) {
        size_t grow = row0 + wm + mi*32 + rb + (r & 3) + 8 * (r >> 2);
        size_t gcol = col0 + wn + ni*32 + rl;
        float v = acc[mi][ni][r];
        if constexpr (MODE == 0) {
          int sel = (int)(gcol >> 10);
          int hh  = ((int)gcol >> 6) & 15;
          int dd  = (int)gcol & 63;
          f16* dst = (sel == 0) ? o0 : ((sel == 1) ? o1 : o2);
          if (sel == 0) v *= 0.045084229f;   // (1/32) * log2(e): exp2-domain scores
          size_t bh = (grow >> 11) * 16 + hh;
          dst[(bh * T_SEQ + (grow & 2047)) * DHEAD + dd] = (f16)v;
        } else if constexpr (MODE == 1 || MODE == 3) {
          size_t idx = grow * D_MODEL + gcol;
          outf[idx] = v + bias[gcol] + resid[idx];
        } else {  // MODE 2
          float t = v + bias[gcol];
          o0[grow * (size_t)DFF + gcol] = (f16)(t > 0.f ? t : 0.f);
        }
      }
    }
  }
}

// MFMA flash attention, S^T formulation + fixed-max softmax.
// Grid/balance = round-2 proven: 512 blocks, 4 waves x 32 q-rows, TWO q-tiles
// per block (qi=15-bx then bx) -> uniform 34 k-tiles/block, perfectly
// load-balanced, 2 blocks/CU co-resident. (r3/r4 lesson: non-uniform
// one-tile blocks all co-resident => no backfill, long heavy-block tail.)
// NEW vs r2: K/V LDS double-buffered + depth-1 register prefetch -> ONE
// barrier per tile (was 2) and global K/V latency hidden under compute.
// Buffer safety: at iter t, writes go to buf[(t+1)&1] whose last readers
// (iter t-1) finished before the end-of-(t-1) barrier; compute reads
// buf[t&1] written the previous iteration across that same barrier.
// setprio(1) wraps the MFMA clusters (T5: 2 blocks/CU at different phases).
// Scores arrive already in log2 domain (q scaled by log2e/32 at QKV epilogue),
// softmax max fixed at 0 (exp2 cannot overflow; softmax shift-invariant).
// S^T = K*Q^T puts each q-row's keys in ONE lane's registers: no per-tile
// shuffles; P^T lane data is key-contiguous -> b64 LDS writes, b128 A-frag reads.
__global__ __launch_bounds__(256) void attn_mfma(
    const f16* __restrict__ qb, const f16* __restrict__ kb,
    const f16* __restrict__ vb, f16* __restrict__ attnb)
{
  constexpr int KT  = 64;
  constexpr int LDK = 72;                        // padded f16 stride (K, Vt, Pt)
  __shared__ __align__(16) f16 Kl[2][KT * LDK];  // [buf][key][d]      18.4 KB
  __shared__ __align__(16) f16 Vt[2][DHEAD * LDK];// [buf][d][key]     18.4 KB
  __shared__ __align__(16) f16 Pt[4 * 32 * LDK]; // per-wave [q][key]  18.4 KB

  int tid  = threadIdx.x;
  int lane = tid & 63, wave = tid >> 6;
  int n    = lane & 15, quad = lane >> 4;
  int quad4 = quad * 4;
  int bh   = blockIdx.y;

  const f16* qg = qb + (size_t)bh * T_SEQ * DHEAD;
  const f16* kg = kb + (size_t)bh * T_SEQ * DHEAD;
  const f16* vg = vb + (size_t)bh * T_SEQ * DHEAD;
  f16* Ptw = Pt + wave * 32 * LDK;
  size_t orow = (size_t)(bh >> 4) * T_SEQ;
  int hcol = (bh & 15) * DHEAD;

  // staging geometry (constant per thread)
  int skey0 = tid >> 3,  sdq = tid & 7;          // K halves: keys skey0, skey0+32
  int kp = tid & 31, dblk = tid >> 5;            // V: keys 2kp,2kp+1; d = dblk*8+e

  #pragma unroll
  for (int pass = 0; pass < 2; ++pass) {
    int qi = pass == 0 ? (15 - (int)blockIdx.x) : (int)blockIdx.x;  // heavy first
    int qw = qi * 128 + wave * 32;               // this wave's first q row

    // Q fragments (B-operand): lane n holds Q[q=qw+ni*16+n][d=quad*8+j]
    f16x8 qfrag[2][2];
    #pragma unroll
    for (int ni = 0; ni < 2; ++ni)
      #pragma unroll
      for (int kj = 0; kj < 2; ++kj)
        qfrag[ni][kj] = *(const f16x8*)(qg + (size_t)(qw + ni*16 + n)*DHEAD + kj*32 + quad*8);

    f32x4 o[2][4];
    #pragma unroll
    for (int mb = 0; mb < 2; ++mb)
      #pragma unroll
      for (int di = 0; di < 4; ++di) o[mb][di] = f32x4{0.f,0.f,0.f,0.f};
    float lsum[2] = {0.f, 0.f};

    int ntiles = 2 * qi + 2;

    // ---- pipeline prologue: tile 0 -> regs -> buf0; issue tile 1 -> regs.
    // buf0 writes are safe: previous pass's last readers finished before its
    // final end-of-iter barrier.
    uint4 kpre0 = *(const uint4*)(kg + (size_t)skey0 * DHEAD + sdq * 8);
    uint4 kpre1 = *(const uint4*)(kg + (size_t)(skey0 + 32) * DHEAD + sdq * 8);
    H8 vpa = *(const H8*)(vg + (size_t)(2*kp) * DHEAD + dblk * 8);
    H8 vpb = *(const H8*)(vg + (size_t)(2*kp) * DHEAD + DHEAD + dblk * 8);
    *(uint4*)(&Kl[0][0] + skey0 * LDK + sdq * 8) = kpre0;
    *(uint4*)(&Kl[0][0] + (skey0 + 32) * LDK + sdq * 8) = kpre1;
    #pragma unroll
    for (int e = 0; e < 8; ++e) {
      f16x2 pk2; pk2[0] = vpa.h[e]; pk2[1] = vpb.h[e];
      *(f16x2*)(&Vt[0][0] + (dblk*8 + e) * LDK + 2*kp) = pk2;
    }
    if (ntiles > 1) {
      kpre0 = *(const uint4*)(kg + (size_t)(KT + skey0) * DHEAD + sdq * 8);
      kpre1 = *(const uint4*)(kg + (size_t)(KT + skey0 + 32) * DHEAD + sdq * 8);
      vpa = *(const H8*)(vg + (size_t)(KT + 2*kp) * DHEAD + dblk * 8);
      vpb = *(const H8*)(vg + (size_t)(KT + 2*kp) * DHEAD + DHEAD + dblk * 8);
    }
    __syncthreads();

    for (int kt = 0; kt < ntiles; ++kt) {
      int kt0 = kt * KT;
      // stage tile kt+1 (already in regs) into the other buffer; issue kt+2
      if (kt + 1 < ntiles) {
        f16* Kn = &Kl[(kt + 1) & 1][0];
        f16* Vn = &Vt[(kt + 1) & 1][0];
        *(uint4*)(Kn + skey0 * LDK + sdq * 8) = kpre0;
        *(uint4*)(Kn + (skey0 + 32) * LDK + sdq * 8) = kpre1;
        #pragma unroll
        for (int e = 0; e < 8; ++e) {
          f16x2 pk2; pk2[0] = vpa.h[e]; pk2[1] = vpb.h[e];
          *(f16x2*)(Vn + (dblk*8 + e) * LDK + 2*kp) = pk2;
        }
        if (kt + 2 < ntiles) {
          int nt0 = kt0 + 2 * KT;
          kpre0 = *(const uint4*)(kg + (size_t)(nt0 + skey0) * DHEAD + sdq * 8);
          kpre1 = *(const uint4*)(kg + (size_t)(nt0 + skey0 + 32) * DHEAD + sdq * 8);
          vpa = *(const H8*)(vg + (size_t)(nt0 + 2*kp) * DHEAD + dblk * 8);
          vpb = *(const H8*)(vg + (size_t)(nt0 + 2*kp) * DHEAD + DHEAD + dblk * 8);
        }
      }

      if (kt0 <= qw + 31) {                      // not fully masked for this wave
        const f16* Kc = &Kl[kt & 1][0];
        const f16* Vc = &Vt[kt & 1][0];
        bool need_mask = (kt0 + KT - 1) > qw;    // diagonal tile

        // S^T = K Q^T : [64 key][32 q]; lane holds (key=mi*16+quad4+r, q=ni*16+n)
        f32x4 st[4][2];
        #pragma unroll
        for (int mi = 0; mi < 4; ++mi)
          #pragma unroll
          for (int ni = 0; ni < 2; ++ni) st[mi][ni] = f32x4{0.f,0.f,0.f,0.f};
        __builtin_amdgcn_s_setprio(1);
        #pragma unroll
        for (int kj = 0; kj < 2; ++kj) {
          #pragma unroll
          for (int mi = 0; mi < 4; ++mi) {
            f16x8 kf = *(const f16x8*)(Kc + (mi*16 + n) * LDK + kj*32 + quad*8);
            #pragma unroll
            for (int ni = 0; ni < 2; ++ni)
              st[mi][ni] = __builtin_amdgcn_mfma_f32_16x16x32_f16(kf, qfrag[ni][kj], st[mi][ni], 0, 0, 0);
          }
        }
        __builtin_amdgcn_s_setprio(0);

        // p = exp2(s'); per-lane row-sum accumulate; P^T -> LDS (b64, key-contig)
        #pragma unroll
        for (int ni = 0; ni < 2; ++ni) {
          #pragma unroll
          for (int mi = 0; mi < 4; ++mi) {
            f16x4 pk;
            #pragma unroll
            for (int r = 0; r < 4; ++r) {
              float sv = st[mi][ni][r];
              if (need_mask) {
                int key = kt0 + mi*16 + quad4 + r;
                int qq  = qw  + ni*16 + n;
                if (key > qq) sv = -1e30f;
              }
              float p = __builtin_amdgcn_exp2f(sv);
              lsum[ni] += p;
              pk[r] = (f16)p;
            }
            *(f16x4*)(Ptw + (ni*16 + n) * LDK + mi*16 + quad4) = pk;
          }
        }

        // O += P V : A-frag = Pt rows (b128, same-wave RAW), B-frag = Vt rows
        __builtin_amdgcn_s_setprio(1);
        #pragma unroll
        for (int kj = 0; kj < 2; ++kj) {
          f16x8 pf[2];
          #pragma unroll
          for (int mb = 0; mb < 2; ++mb)
            pf[mb] = *(const f16x8*)(Ptw + (mb*16 + n) * LDK + kj*32 + quad*8);
          #pragma unroll
          for (int di = 0; di < 4; ++di) {
            f16x8 vf = *(const f16x8*)(Vc + (di*16 + n) * LDK + kj*32 + quad*8);
            #pragma unroll
            for (int mb = 0; mb < 2; ++mb)
              o[mb][di] = __builtin_amdgcn_mfma_f32_16x16x32_f16(pf[mb], vf, o[mb][di], 0, 0, 0);
          }
        }
        __builtin_amdgcn_s_setprio(0);
      }
      __syncthreads();                           // single barrier per tile
    }

    // finish l: quads hold disjoint key-subsets of each q-row -> 2 shuffles
    #pragma unroll
    for (int ni = 0; ni < 2; ++ni) {
      lsum[ni] += __shfl_xor(lsum[ni], 16, 64);
      lsum[ni] += __shfl_xor(lsum[ni], 32, 64);
    }
    // epilogue: O C-layout lane holds (q=mb*16+quad4+r, d=di*16+n)
    #pragma unroll
    for (int mb = 0; mb < 2; ++mb) {
      #pragma unroll
      for (int r = 0; r < 4; ++r) {
        float lv  = __shfl(lsum[mb], quad4 + r, 64);   // lane n'=quad4+r holds q's sum
        float inv = 1.f / lv;
        int t = qw + mb*16 + quad4 + r;
        #pragma unroll
        for (int di = 0; di < 4; ++di)
          attnb[(orow + t) * D_MODEL + hcol + di*16 + n] = (f16)(o[mb][di][r] * inv);
      }
    }
  }
}

extern "C" void kernel_launch(void* const* d_in, const int* in_sizes, int n_in,
                              void* d_out, int out_size, void* d_ws, size_t ws_size,
                              hipStream_t stream)
{
  const float* x     = (const float*)d_in[0];
  const float* Wq    = (const float*)d_in[1];
  const float* Wk    = (const float*)d_in[2];
  const float* Wv    = (const float*)d_in[3];
  const float* Wproj = (const float*)d_in[4];
  const float* bproj = (const float*)d_in[5];
  const float* W1    = (const float*)d_in[6];
  const float* b1    = (const float*)d_in[7];
  const float* W2    = (const float*)d_in[8];
  const float* b2    = (const float*)d_in[9];
  const float* g1    = (const float*)d_in[10];
  const float* bt1   = (const float*)d_in[11];
  const float* g2    = (const float*)d_in[12];
  const float* bt2   = (const float*)d_in[13];
  float* out = (float*)d_out;
  (void)in_sizes; (void)n_in; (void)out_size; (void)ws_size;

  char* ws = (char*)d_ws;
  const size_t SZ_H16 = (size_t)NTOK * D_MODEL * 2;  // 16.78 MB
  const size_t SZ_F32 = (size_t)NTOK * D_MODEL * 4;  // 33.55 MB
  f16*   qb      = (f16*)(ws + 0);
  f16*   kb      = (f16*)(ws + 1 * SZ_H16);
  f16*   vb      = (f16*)(ws + 2 * SZ_H16);
  f16*   attnb   = (f16*)(ws + 3 * SZ_H16);
  f16*   hbuf    = (f16*)(ws + 0);                   // reuses q/k/v/attn after proj (67.1MB)
  float* x1f     = (float*)(ws + 4 * SZ_H16);        // becomes x2 in-place at proj
  f16*   x1h     = (f16*)(ws + 4 * SZ_H16 + SZ_F32);
  float* x3f     = (float*)(ws + 5 * SZ_H16 + SZ_F32);
  f16*   x3h     = (f16*)(ws + 5 * SZ_H16 + 2 * SZ_F32);
  char*  wb      = ws + 6 * SZ_H16 + 2 * SZ_F32;
  f16*   Wqkv_t  = (f16*)(wb);                                       // [3072][1024]
  f16*   Wproj_t = (f16*)(wb + (size_t)3072*1024*2);                 // [1024][1024]
  f16*   W1_t    = (f16*)(wb + (size_t)(3072+1024)*1024*2);          // [4096][1024]
  f16*   W2_t    = (f16*)(wb + (size_t)(3072+1024+4096)*1024*2);     // [1024][4096]

  dim3 blk(256), blk5(512);
  // ---- pack all weights to f16 B^T layouts (single fused launch)
  transpose_all<<<dim3(12288), blk, 0, stream>>>(Wq, Wk, Wv, Wproj, W1, W2,
                                                 Wqkv_t, Wproj_t, W1_t, W2_t);
  // ---- ln1
  ln_kernel<<<NTOK, blk, 0, stream>>>(x, g1, bt1, x1f, x1h);
  // ---- fused QKV gemm [8192,1024] x [1024,3072]   (BN=128: 768 wg = 3 full rounds)
  gemm8<0,128><<<dim3(32, 24), blk5, 0, stream>>>(x1h, Wqkv_t, 1024, nullptr, nullptr, nullptr, qb, kb, vb);
  // ---- attention (MFMA flash, balanced two-pass blocks, dbuf pipeline)
  attn_mfma<<<dim3(8, 64), blk, 0, stream>>>(qb, kb, vb, attnb);
  // ---- proj + bias + residual(x1) -> x2 (in place over x1f)  (256 wg = 1 round)
  gemm8<1,128><<<dim3(32, 8), blk5, 0, stream>>>(attnb, Wproj_t, 1024, bproj, x1f, x1f, nullptr, nullptr, nullptr);
  // ---- ln2
  ln_kernel<<<NTOK, blk, 0, stream>>>(x1f, g2, bt2, x3f, x3h);
  // ---- ffn1: relu(x3 @ W1 + b1)   (BN=256: 512 wg = 2 full rounds)
  gemm8<2,256><<<dim3(32, 16), blk5, 0, stream>>>(x3h, W1_t, 1024, b1, nullptr, nullptr, hbuf, nullptr, nullptr);
  // ---- ffn2: x3 + h @ W2 + b2 -> out   (256 wg = 1 round)
  gemm8<3,128><<<dim3(32, 8), blk5, 0, stream>>>(hbuf, W2_t, 4096, b2, x3f, out, nullptr, nullptr, nullptr);
}

// Round 7
// 495.629 us; speedup vs baseline: 1.2415x; 1.0388x over previous
//
#include <hip/hip_runtime.h>
#include <cstdint>

typedef _Float16 f16;
typedef __attribute__((ext_vector_type(8))) _Float16 f16x8;
typedef __attribute__((ext_vector_type(4))) _Float16 f16x4;
typedef __attribute__((ext_vector_type(2))) _Float16 f16x2;
typedef __attribute__((ext_vector_type(4))) float f32x4;
typedef __attribute__((ext_vector_type(16))) float f32x16;

#define D_MODEL 1024
#define T_SEQ   2048
#define NTOK    8192      // B*T
#define DFF     4096
#define DHEAD   64

struct alignas(16) H8 { f16 h[8]; };

// async global->LDS, 16B per lane. LDS dest must be wave-uniform base; HW adds lane*16.
__device__ __forceinline__ void load_lds16(const void* gp, void* lp) {
  __builtin_amdgcn_global_load_lds(
      (const __attribute__((address_space(1))) unsigned int*)(unsigned long long)(uintptr_t)gp,
      (__attribute__((address_space(3))) unsigned int*)(unsigned int)(uintptr_t)lp,
      16, 0, 0);
}

// raw phase barrier: no vmcnt(0) drain (unlike __syncthreads), but full
// compiler fence so LDS reads/writes can't migrate across phases.
__device__ __forceinline__ void phase_bar() {
  asm volatile("" ::: "memory");
  __builtin_amdgcn_sched_barrier(0);
  __builtin_amdgcn_s_barrier();
  __builtin_amdgcn_sched_barrier(0);
  asm volatile("" ::: "memory");
}

__device__ __forceinline__ void wait_vm2() {
  asm volatile("s_waitcnt vmcnt(2)" ::: "memory");
  __builtin_amdgcn_sched_barrier(0);
}
__device__ __forceinline__ void wait_vm0() {
  asm volatile("s_waitcnt vmcnt(0)" ::: "memory");
  __builtin_amdgcn_sched_barrier(0);
}

// ---------------------------------------------------------------------------
// All six weight transposes fused into ONE kernel (was 6 launches):
// out[c][r] = (f16) in[r][c]. 12288 blocks x one 32x32 tile each.
// ranges: [0,3072) Wq/Wk/Wv (16 slices of [1024][64] each)
//         [3072,4096) Wproj [1024][1024]
//         [4096,8192) W1 [1024][4096]
//         [8192,12288) W2 [4096][1024]
// ---------------------------------------------------------------------------
__global__ __launch_bounds__(256) void transpose_all(
    const float* __restrict__ Wq, const float* __restrict__ Wk,
    const float* __restrict__ Wv, const float* __restrict__ Wproj,
    const float* __restrict__ W1, const float* __restrict__ W2,
    f16* __restrict__ Wqkv_t, f16* __restrict__ Wproj_t,
    f16* __restrict__ W1_t, f16* __restrict__ W2_t)
{
  __shared__ float tile[32][33];
  int b = blockIdx.x;
  const float* in; f16* out; int rows, cols, r0, c0;
  if (b < 3072) {
    int j = b >> 10;                       // 0,1,2 -> q,k,v
    int local = b & 1023;
    int slice = local >> 6;                // 64 tiles per [1024][64] slice
    int tl = local & 63;
    in  = (j == 0 ? Wq : (j == 1 ? Wk : Wv)) + (size_t)slice * 65536;
    out = Wqkv_t + (size_t)j * 1024 * 1024 + (size_t)slice * 65536;
    rows = 1024; cols = 64;
    r0 = (tl & 31) * 32; c0 = (tl >> 5) * 32;
  } else if (b < 4096) {
    int tl = b - 3072;
    in = Wproj; out = Wproj_t; rows = 1024; cols = 1024;
    r0 = (tl & 31) * 32; c0 = (tl >> 5) * 32;
  } else if (b < 8192) {
    int tl = b - 4096;
    in = W1; out = W1_t; rows = 1024; cols = 4096;
    r0 = (tl & 31) * 32; c0 = (tl >> 5) * 32;
  } else {
    int tl = b - 8192;
    in = W2; out = W2_t; rows = 4096; cols = 1024;
    r0 = (tl & 127) * 32; c0 = (tl >> 7) * 32;
  }
  int tx = threadIdx.x & 31, ty = threadIdx.x >> 5;   // 32 x 8
  #pragma unroll
  for (int i = 0; i < 4; ++i)
    tile[ty + i*8][tx] = in[(size_t)(r0 + ty + i*8)*cols + c0 + tx];
  __syncthreads();
  #pragma unroll
  for (int i = 0; i < 4; ++i)
    out[(size_t)(c0 + ty + i*8)*rows + r0 + tx] = (f16)tile[tx][ty + i*8];
}

// row-wise layernorm over 1024; writes fp32 (residual path) + f16 (GEMM input)
__global__ __launch_bounds__(256) void ln_kernel(
    const float* __restrict__ x, const float* __restrict__ g, const float* __restrict__ b,
    float* __restrict__ outf, f16* __restrict__ outh)
{
  int row = blockIdx.x;
  const float* xr = x + (size_t)row * D_MODEL;
  int tid = threadIdx.x;
  float v[4];
  float s = 0.f;
  #pragma unroll
  for (int i = 0; i < 4; ++i) { v[i] = xr[tid + i*256]; s += v[i]; }
  #pragma unroll
  for (int off = 32; off > 0; off >>= 1) s += __shfl_down(s, off, 64);
  __shared__ float red1[4], red2[4];
  if ((tid & 63) == 0) red1[tid >> 6] = s;
  __syncthreads();
  float mean = (red1[0] + red1[1] + red1[2] + red1[3]) * (1.f / D_MODEL);
  float s2 = 0.f;
  #pragma unroll
  for (int i = 0; i < 4; ++i) { float d = v[i] - mean; s2 += d * d; }
  #pragma unroll
  for (int off = 32; off > 0; off >>= 1) s2 += __shfl_down(s2, off, 64);
  if ((tid & 63) == 0) red2[tid >> 6] = s2;
  __syncthreads();
  float var = (red2[0] + red2[1] + red2[2] + red2[3]) * (1.f / D_MODEL);
  float rstd = rsqrtf(var + 1e-5f);
  #pragma unroll
  for (int i = 0; i < 4; ++i) {
    int c = tid + i*256;
    float y = (v[i] - mean) * rstd * g[c] + b[c];
    outf[(size_t)row*D_MODEL + c] = y;
    outh[(size_t)row*D_MODEL + c] = (f16)y;
  }
}

// ---------------------------------------------------------------------------
// 256xBN phased GEMM (plain-HIP port of the 8-phase template, T2+T3+T4+T5):
//   C[M,N] = A[M,K] * BT[N,K]^T, f16 in, fp32 acc, 32x32x16 MFMA.
//   512 threads = 8 waves; BN=256 -> waves 2Mx4N (wave tile 128x64, MI=4);
//   BN=128 -> waves 4Mx2N (wave tile 64x64, MI=2).
//   Double-buffered LDS (BN=256: 128 KB, BN=128: 96 KB), 1 block/CU.
//   Per K-tile: 4 phases (BN=256) of {ds-read frags || stage 1 half-tile ->
//   barrier -> setprio(1) 8xMFMA setprio(0) -> barrier}; counted vmcnt(2)
//   ONCE per K-tile (never 0 in steady state) keeps the next tile's
//   global_load_lds in flight across barriers. A-frags cached across the two
//   ni-phases of an mi-pair; B-frags cached across mi-pairs -> phase 4 is
//   pure-MFMA, so the same-buffer A0 prefetch it issues is barrier-safe.
//   Bank swizzle (BK=64 rows = 128B = full bank wrap): LDS slot (row,pos)
//   holds global k-chunk (pos ^ (row&7)); reads use chunk = logical ^ (rl&7).
// MODE 0: scatter q/k/v (q scaled log2e/32) -> o0,o1,o2 [BH][T][64] f16
// MODE 1: outf = acc + bias[col] + resid[idx]            (proj, fp32)
// MODE 2: o0   = relu(acc + bias[col])                   (ffn1, f16, ld 4096)
// MODE 3: outf = acc + bias[col] + resid[idx]            (ffn2 -> d_out)
// ---------------------------------------------------------------------------

#define STAGE_H(gbase, h, ldst, k0)                                            \
  { _Pragma("unroll")                                                          \
    for (int j_ = 0; j_ < 2; ++j_) {                                           \
      int c_  = tid + j_*512;                                                  \
      int rr_ = c_ >> 3;                                                       \
      int cg_ = (c_ & 7) ^ (rr_ & 7);                                          \
      load_lds16((gbase) + (size_t)((h)*128 + rr_) * K + (k0) + cg_*8,         \
                 (ldst) + (h)*128*64 + (size_t)(c_ & ~63) * 8);                \
    } }

#define LDS_A(bsel, mp)                                                        \
  { _Pragma("unroll")                                                          \
    for (int i_ = 0; i_ < 2; ++i_)                                             \
      _Pragma("unroll")                                                        \
      for (int ks_ = 0; ks_ < 4; ++ks_)                                        \
        fa[i_][ks_] = *(const f16x8*)(&As[bsel][                               \
            (wm + ((mp)*2 + i_)*32 + rl)*64 + (((ks_*2 + hl) ^ sw)*8)]); }

#define LDS_B(bsel, ni, fb)                                                    \
  { _Pragma("unroll")                                                          \
    for (int ks_ = 0; ks_ < 4; ++ks_)                                          \
      fb[ks_] = *(const f16x8*)(&Bs[bsel][                                     \
          (wn + (ni)*32 + rl)*64 + (((ks_*2 + hl) ^ sw)*8)]); }

#define MFMA8(mp, ni, fb)                                                      \
  { __builtin_amdgcn_s_setprio(1);                                             \
    _Pragma("unroll")                                                          \
    for (int ks_ = 0; ks_ < 4; ++ks_) {                                        \
      acc[(mp)*2+0][ni] = __builtin_amdgcn_mfma_f32_32x32x16_f16(              \
          fa[0][ks_], fb[ks_], acc[(mp)*2+0][ni], 0, 0, 0);                    \
      acc[(mp)*2+1][ni] = __builtin_amdgcn_mfma_f32_32x32x16_f16(              \
          fa[1][ks_], fb[ks_], acc[(mp)*2+1][ni], 0, 0, 0);                    \
    }                                                                          \
    __builtin_amdgcn_s_setprio(0); }

template<int MODE, int BN>
__global__ __launch_bounds__(512, 2) void gemm8(
    const f16* __restrict__ A, const f16* __restrict__ BT, int K,
    const float* __restrict__ bias, const float* __restrict__ resid,
    float* __restrict__ outf, f16* __restrict__ o0, f16* __restrict__ o1, f16* __restrict__ o2)
{
  constexpr int BM  = 256;
  constexpr int NWN = BN / 64;            // waves along N (4 or 2)
  constexpr int MI  = (BM / (8 / NWN)) / 32;  // mi frags per wave (4 or 2)

  __shared__ __align__(16) f16 As[2][BM * 64];
  __shared__ __align__(16) f16 Bs[2][BN * 64];

  int tid  = threadIdx.x;
  int lane = tid & 63;
  int wave = tid >> 6;
  int rl = lane & 31, hl = lane >> 5;
  int sw = rl & 7;
  int wmi = wave / NWN, wni = wave % NWN;
  int wm = wmi * (MI * 32), wn = wni * 64;

  // XCD swizzle, A-panel-major (r6 lesson: ffn2's 67MB A was streamed once
  // per column-block -> 282MB FETCH). Each XCD gets a contiguous sid chunk;
  // within it, consecutive sids share bx (same A panel) and span all by.
  // Same-A blocks are co-resident on one XCD and walk K in lockstep, so the
  // instantaneous L2 working set is ~(4 A-chunks + gy B-chunks) << 4MB ->
  // A and B each fetched ~once per XCD from HBM. Bijective: bx=sid/gy<gx.
  int gx  = gridDim.x;
  int gy  = gridDim.y;
  int nwg = gx * gy;
  int lin = blockIdx.x + gx * blockIdx.y;
  int sid = (nwg & 7) == 0 ? ((lin & 7) * (nwg >> 3) + (lin >> 3)) : lin;
  int bx  = sid / gy, by = sid % gy;

  size_t row0 = (size_t)bx * BM, col0 = (size_t)by * BN;
  const f16* a_base = A  + row0 * K;
  const f16* b_base = BT + col0 * K;
  int NT = K >> 6;

  f32x16 acc[MI][2];
  #pragma unroll
  for (int i = 0; i < MI; ++i)
    #pragma unroll
    for (int j = 0; j < 2; ++j)
      acc[i][j] = (f32x16)(0.f);

  f16x8 fa[2][4], fb0[4], fb1[4];

  if constexpr (BN == 256) {
    // ---- prologue: tile0 (A0,A1,B0,B1) + tile1 A0 in flight
    STAGE_H(a_base, 0, &As[0][0], 0);
    STAGE_H(a_base, 1, &As[0][0], 0);
    STAGE_H(b_base, 0, &Bs[0][0], 0);
    STAGE_H(b_base, 1, &Bs[0][0], 0);
    if (NT > 1) { STAGE_H(a_base, 0, &As[1][0], 64); wait_vm2(); }
    else        { wait_vm0(); }
    phase_bar();

    for (int t = 0; t < NT; ++t) {
      int cur = t & 1, nxt = cur ^ 1;
      int k1 = (t + 1) << 6, k2 = (t + 2) << 6;
      bool s1 = (t + 1) < NT, s2 = (t + 2) < NT;
      // ph1: (mi-pair 0, ni 0); prefetch (t+1).A1 -> other buffer
      LDS_A(cur, 0); LDS_B(cur, 0, fb0);
      if (s1) STAGE_H(a_base, 1, &As[nxt][0], k1);
      phase_bar();
      MFMA8(0, 0, fb0);
      phase_bar();
      // ph2: (0, 1); prefetch (t+1).B0
      LDS_B(cur, 1, fb1);
      if (s1) STAGE_H(b_base, 0, &Bs[nxt][0], k1);
      phase_bar();
      MFMA8(0, 1, fb1);
      phase_bar();
      // ph3: (1, 0) — fb0 cached; prefetch (t+1).B1
      LDS_A(cur, 1);
      if (s1) STAGE_H(b_base, 1, &Bs[nxt][0], k1);
      phase_bar();
      MFMA8(1, 0, fb0);
      phase_bar();
      // ph4: (1, 1) — pure MFMA; prefetch (t+2).A0 into the buffer this
      // iteration just finished reading (all A reads done by end of ph3).
      if (s2) STAGE_H(a_base, 0, &As[cur][0], k2);
      phase_bar();
      MFMA8(1, 1, fb1);
      if (s2) wait_vm2(); else wait_vm0();   // (t+1) fully landed; (t+2).A0 in flight
      phase_bar();
    }
  } else {
    // ---- BN=128: MI=2, 2 phases per K-tile, 2 K-tiles per iteration.
    // buffers fixed by tile parity. B has a single 128-row half.
    STAGE_H(a_base, 0, &As[0][0], 0);
    STAGE_H(a_base, 1, &As[0][0], 0);
    STAGE_H(b_base, 0, &Bs[0][0], 0);
    if (NT > 1) { STAGE_H(a_base, 0, &As[1][0], 64); wait_vm2(); }
    else        { wait_vm0(); }
    phase_bar();

    for (int t = 0; t < NT; t += 2) {
      int k1 = (t + 1) << 6, k2 = (t + 2) << 6, k3 = (t + 3) << 6;
      bool s1 = (t + 1) < NT, s2 = (t + 2) < NT, s3 = (t + 3) < NT;
      // ph1: tile t (buf0), ni0; prefetch (t+1).A1 + (t+1).B -> buf1
      LDS_A(0, 0); LDS_B(0, 0, fb0);
      if (s1) { STAGE_H(a_base, 1, &As[1][0], k1); STAGE_H(b_base, 0, &Bs[1][0], k1); }
      phase_bar();
      MFMA8(0, 0, fb0);
      phase_bar();
      // ph2: tile t, ni1; prefetch (t+2).A0 -> buf0 (A reads done at ph1)
      LDS_B(0, 1, fb1);
      if (s2) STAGE_H(a_base, 0, &As[0][0], k2);
      phase_bar();
      MFMA8(0, 1, fb1);
      if (s2) wait_vm2(); else wait_vm0();   // (t+1) landed; (t+2).A0 in flight
      phase_bar();
      if (!s1) break;
      // ph3: tile t+1 (buf1), ni0; prefetch (t+2).A1 + (t+2).B -> buf0
      LDS_A(1, 0); LDS_B(1, 0, fb0);
      if (s2) { STAGE_H(a_base, 1, &As[0][0], k2); STAGE_H(b_base, 0, &Bs[0][0], k2); }
      phase_bar();
      MFMA8(0, 0, fb0);
      phase_bar();
      // ph4: tile t+1, ni1; prefetch (t+3).A0 -> buf1
      LDS_B(1, 1, fb1);
      if (s3) STAGE_H(a_base, 0, &As[1][0], k3);
      phase_bar();
      MFMA8(0, 1, fb1);
      if (s3) wait_vm2(); else wait_vm0();   // (t+2) landed; (t+3).A0 in flight
      phase_bar();
    }
  }

  // epilogue: 32x32 C layout (m74/m101): col=lane&31, row=(reg&3)+8*(reg>>2)+4*(lane>>5)
  int rb = hl * 4;
  #pragma unroll
  for (int mi = 0; mi < MI; ++mi) {
    #pragma unroll
    for (int ni = 0; ni < 2; ++ni) {
      #pragma unroll
      for (int r = 0; r < 16; ++r) {
        size_t grow = row0 + wm + mi*32 + rb + (r & 3) + 8 * (r >> 2);
        size_t gcol = col0 + wn + ni*32 + rl;
        float v = acc[mi][ni][r];
        if constexpr (MODE == 0) {
          int sel = (int)(gcol >> 10);
          int hh  = ((int)gcol >> 6) & 15;
          int dd  = (int)gcol & 63;
          f16* dst = (sel == 0) ? o0 : ((sel == 1) ? o1 : o2);
          if (sel == 0) v *= 0.045084229f;   // (1/32) * log2(e): exp2-domain scores
          size_t bh = (grow >> 11) * 16 + hh;
          dst[(bh * T_SEQ + (grow & 2047)) * DHEAD + dd] = (f16)v;
        } else if constexpr (MODE == 1 || MODE == 3) {
          size_t idx = grow * D_MODEL + gcol;
          outf[idx] = v + bias[gcol] + resid[idx];
        } else {  // MODE 2
          float t = v + bias[gcol];
          o0[grow * (size_t)DFF + gcol] = (f16)(t > 0.f ? t : 0.f);
        }
      }
    }
  }
}

// MFMA flash attention, S^T formulation + fixed-max softmax.
// Grid/balance = round-2 proven: 512 blocks, 4 waves x 32 q-rows, TWO q-tiles
// per block (qi=15-bx then bx) -> uniform 34 k-tiles/block, perfectly
// load-balanced, 2 blocks/CU co-resident. (r3/r4 lesson: non-uniform
// one-tile blocks all co-resident => no backfill, long heavy-block tail.)
// NEW vs r2: K/V LDS double-buffered + depth-1 register prefetch -> ONE
// barrier per tile (was 2) and global K/V latency hidden under compute.
// Buffer safety: at iter t, writes go to buf[(t+1)&1] whose last readers
// (iter t-1) finished before the end-of-(t-1) barrier; compute reads
// buf[t&1] written the previous iteration across that same barrier.
// setprio(1) wraps the MFMA clusters (T5: 2 blocks/CU at different phases).
// Scores arrive already in log2 domain (q scaled by log2e/32 at QKV epilogue),
// softmax max fixed at 0 (exp2 cannot overflow; softmax shift-invariant).
// S^T = K*Q^T puts each q-row's keys in ONE lane's registers: no per-tile
// shuffles; P^T lane data is key-contiguous -> b64 LDS writes, b128 A-frag reads.
__global__ __launch_bounds__(256) void attn_mfma(
    const f16* __restrict__ qb, const f16* __restrict__ kb,
    const f16* __restrict__ vb, f16* __restrict__ attnb)
{
  constexpr int KT  = 64;
  constexpr int LDK = 72;                        // padded f16 stride (K, Vt, Pt)
  __shared__ __align__(16) f16 Kl[2][KT * LDK];  // [buf][key][d]      18.4 KB
  __shared__ __align__(16) f16 Vt[2][DHEAD * LDK];// [buf][d][key]     18.4 KB
  __shared__ __align__(16) f16 Pt[4 * 32 * LDK]; // per-wave [q][key]  18.4 KB

  int tid  = threadIdx.x;
  int lane = tid & 63, wave = tid >> 6;
  int n    = lane & 15, quad = lane >> 4;
  int quad4 = quad * 4;
  int bh   = blockIdx.y;

  const f16* qg = qb + (size_t)bh * T_SEQ * DHEAD;
  const f16* kg = kb + (size_t)bh * T_SEQ * DHEAD;
  const f16* vg = vb + (size_t)bh * T_SEQ * DHEAD;
  f16* Ptw = Pt + wave * 32 * LDK;
  size_t orow = (size_t)(bh >> 4) * T_SEQ;
  int hcol = (bh & 15) * DHEAD;

  // staging geometry (constant per thread)
  int skey0 = tid >> 3,  sdq = tid & 7;          // K halves: keys skey0, skey0+32
  int kp = tid & 31, dblk = tid >> 5;            // V: keys 2kp,2kp+1; d = dblk*8+e

  #pragma unroll
  for (int pass = 0; pass < 2; ++pass) {
    int qi = pass == 0 ? (15 - (int)blockIdx.x) : (int)blockIdx.x;  // heavy first
    int qw = qi * 128 + wave * 32;               // this wave's first q row

    // Q fragments (B-operand): lane n holds Q[q=qw+ni*16+n][d=quad*8+j]
    f16x8 qfrag[2][2];
    #pragma unroll
    for (int ni = 0; ni < 2; ++ni)
      #pragma unroll
      for (int kj = 0; kj < 2; ++kj)
        qfrag[ni][kj] = *(const f16x8*)(qg + (size_t)(qw + ni*16 + n)*DHEAD + kj*32 + quad*8);

    f32x4 o[2][4];
    #pragma unroll
    for (int mb = 0; mb < 2; ++mb)
      #pragma unroll
      for (int di = 0; di < 4; ++di) o[mb][di] = f32x4{0.f,0.f,0.f,0.f};
    float lsum[2] = {0.f, 0.f};

    int ntiles = 2 * qi + 2;

    // ---- pipeline prologue: tile 0 -> regs -> buf0; issue tile 1 -> regs.
    // buf0 writes are safe: previous pass's last readers finished before its
    // final end-of-iter barrier.
    uint4 kpre0 = *(const uint4*)(kg + (size_t)skey0 * DHEAD + sdq * 8);
    uint4 kpre1 = *(const uint4*)(kg + (size_t)(skey0 + 32) * DHEAD + sdq * 8);
    H8 vpa = *(const H8*)(vg + (size_t)(2*kp) * DHEAD + dblk * 8);
    H8 vpb = *(const H8*)(vg + (size_t)(2*kp) * DHEAD + DHEAD + dblk * 8);
    *(uint4*)(&Kl[0][0] + skey0 * LDK + sdq * 8) = kpre0;
    *(uint4*)(&Kl[0][0] + (skey0 + 32) * LDK + sdq * 8) = kpre1;
    #pragma unroll
    for (int e = 0; e < 8; ++e) {
      f16x2 pk2; pk2[0] = vpa.h[e]; pk2[1] = vpb.h[e];
      *(f16x2*)(&Vt[0][0] + (dblk*8 + e) * LDK + 2*kp) = pk2;
    }
    if (ntiles > 1) {
      kpre0 = *(const uint4*)(kg + (size_t)(KT + skey0) * DHEAD + sdq * 8);
      kpre1 = *(const uint4*)(kg + (size_t)(KT + skey0 + 32) * DHEAD + sdq * 8);
      vpa = *(const H8*)(vg + (size_t)(KT + 2*kp) * DHEAD + dblk * 8);
      vpb = *(const H8*)(vg + (size_t)(KT + 2*kp) * DHEAD + DHEAD + dblk * 8);
    }
    __syncthreads();

    for (int kt = 0; kt < ntiles; ++kt) {
      int kt0 = kt * KT;
      // stage tile kt+1 (already in regs) into the other buffer; issue kt+2
      if (kt + 1 < ntiles) {
        f16* Kn = &Kl[(kt + 1) & 1][0];
        f16* Vn = &Vt[(kt + 1) & 1][0];
        *(uint4*)(Kn + skey0 * LDK + sdq * 8) = kpre0;
        *(uint4*)(Kn + (skey0 + 32) * LDK + sdq * 8) = kpre1;
        #pragma unroll
        for (int e = 0; e < 8; ++e) {
          f16x2 pk2; pk2[0] = vpa.h[e]; pk2[1] = vpb.h[e];
          *(f16x2*)(Vn + (dblk*8 + e) * LDK + 2*kp) = pk2;
        }
        if (kt + 2 < ntiles) {
          int nt0 = kt0 + 2 * KT;
          kpre0 = *(const uint4*)(kg + (size_t)(nt0 + skey0) * DHEAD + sdq * 8);
          kpre1 = *(const uint4*)(kg + (size_t)(nt0 + skey0 + 32) * DHEAD + sdq * 8);
          vpa = *(const H8*)(vg + (size_t)(nt0 + 2*kp) * DHEAD + dblk * 8);
          vpb = *(const H8*)(vg + (size_t)(nt0 + 2*kp) * DHEAD + DHEAD + dblk * 8);
        }
      }

      if (kt0 <= qw + 31) {                      // not fully masked for this wave
        const f16* Kc = &Kl[kt & 1][0];
        const f16* Vc = &Vt[kt & 1][0];
        bool need_mask = (kt0 + KT - 1) > qw;    // diagonal tile

        // S^T = K Q^T : [64 key][32 q]; lane holds (key=mi*16+quad4+r, q=ni*16+n)
        f32x4 st[4][2];
        #pragma unroll
        for (int mi = 0; mi < 4; ++mi)
          #pragma unroll
          for (int ni = 0; ni < 2; ++ni) st[mi][ni] = f32x4{0.f,0.f,0.f,0.f};
        __builtin_amdgcn_s_setprio(1);
        #pragma unroll
        for (int kj = 0; kj < 2; ++kj) {
          #pragma unroll
          for (int mi = 0; mi < 4; ++mi) {
            f16x8 kf = *(const f16x8*)(Kc + (mi*16 + n) * LDK + kj*32 + quad*8);
            #pragma unroll
            for (int ni = 0; ni < 2; ++ni)
              st[mi][ni] = __builtin_amdgcn_mfma_f32_16x16x32_f16(kf, qfrag[ni][kj], st[mi][ni], 0, 0, 0);
          }
        }
        __builtin_amdgcn_s_setprio(0);

        // p = exp2(s'); per-lane row-sum accumulate; P^T -> LDS (b64, key-contig)
        #pragma unroll
        for (int ni = 0; ni < 2; ++ni) {
          #pragma unroll
          for (int mi = 0; mi < 4; ++mi) {
            f16x4 pk;
            #pragma unroll
            for (int r = 0; r < 4; ++r) {
              float sv = st[mi][ni][r];
              if (need_mask) {
                int key = kt0 + mi*16 + quad4 + r;
                int qq  = qw  + ni*16 + n;
                if (key > qq) sv = -1e30f;
              }
              float p = __builtin_amdgcn_exp2f(sv);
              lsum[ni] += p;
              pk[r] = (f16)p;
            }
            *(f16x4*)(Ptw + (ni*16 + n) * LDK + mi*16 + quad4) = pk;
          }
        }

        // O += P V : A-frag = Pt rows (b128, same-wave RAW), B-frag = Vt rows
        __builtin_amdgcn_s_setprio(1);
        #pragma unroll
        for (int kj = 0; kj < 2; ++kj) {
          f16x8 pf[2];
          #pragma unroll
          for (int mb = 0; mb < 2; ++mb)
            pf[mb] = *(const f16x8*)(Ptw + (mb*16 + n) * LDK + kj*32 + quad*8);
          #pragma unroll
          for (int di = 0; di < 4; ++di) {
            f16x8 vf = *(const f16x8*)(Vc + (di*16 + n) * LDK + kj*32 + quad*8);
            #pragma unroll
            for (int mb = 0; mb < 2; ++mb)
              o[mb][di] = __builtin_amdgcn_mfma_f32_16x16x32_f16(pf[mb], vf, o[mb][di], 0, 0, 0);
          }
        }
        __builtin_amdgcn_s_setprio(0);
      }
      __syncthreads();                           // single barrier per tile
    }

    // finish l: quads hold disjoint key-subsets of each q-row -> 2 shuffles
    #pragma unroll
    for (int ni = 0; ni < 2; ++ni) {
      lsum[ni] += __shfl_xor(lsum[ni], 16, 64);
      lsum[ni] += __shfl_xor(lsum[ni], 32, 64);
    }
    // epilogue: O C-layout lane holds (q=mb*16+quad4+r, d=di*16+n)
    #pragma unroll
    for (int mb = 0; mb < 2; ++mb) {
      #pragma unroll
      for (int r = 0; r < 4; ++r) {
        float lv  = __shfl(lsum[mb], quad4 + r, 64);   // lane n'=quad4+r holds q's sum
        float inv = 1.f / lv;
        int t = qw + mb*16 + quad4 + r;
        #pragma unroll
        for (int di = 0; di < 4; ++di)
          attnb[(orow + t) * D_MODEL + hcol + di*16 + n] = (f16)(o[mb][di][r] * inv);
      }
    }
  }
}

extern "C" void kernel_launch(void* const* d_in, const int* in_sizes, int n_in,
                              void* d_out, int out_size, void* d_ws, size_t ws_size,
                              hipStream_t stream)
{
  const float* x     = (const float*)d_in[0];
  const float* Wq    = (const float*)d_in[1];
  const float* Wk    = (const float*)d_in[2];
  const float* Wv    = (const float*)d_in[3];
  const float* Wproj = (const float*)d_in[4];
  const float* bproj = (const float*)d_in[5];
  const float* W1    = (const float*)d_in[6];
  const float* b1    = (const float*)d_in[7];
  const float* W2    = (const float*)d_in[8];
  const float* b2    = (const float*)d_in[9];
  const float* g1    = (const float*)d_in[10];
  const float* bt1   = (const float*)d_in[11];
  const float* g2    = (const float*)d_in[12];
  const float* bt2   = (const float*)d_in[13];
  float* out = (float*)d_out;
  (void)in_sizes; (void)n_in; (void)out_size; (void)ws_size;

  char* ws = (char*)d_ws;
  const size_t SZ_H16 = (size_t)NTOK * D_MODEL * 2;  // 16.78 MB
  const size_t SZ_F32 = (size_t)NTOK * D_MODEL * 4;  // 33.55 MB
  f16*   qb      = (f16*)(ws + 0);
  f16*   kb      = (f16*)(ws + 1 * SZ_H16);
  f16*   vb      = (f16*)(ws + 2 * SZ_H16);
  f16*   attnb   = (f16*)(ws + 3 * SZ_H16);
  f16*   hbuf    = (f16*)(ws + 0);                   // reuses q/k/v/attn after proj (67.1MB)
  float* x1f     = (float*)(ws + 4 * SZ_H16);        // becomes x2 in-place at proj
  f16*   x1h     = (f16*)(ws + 4 * SZ_H16 + SZ_F32);
  float* x3f     = (float*)(ws + 5 * SZ_H16 + SZ_F32);
  f16*   x3h     = (f16*)(ws + 5 * SZ_H16 + 2 * SZ_F32);
  char*  wb      = ws + 6 * SZ_H16 + 2 * SZ_F32;
  f16*   Wqkv_t  = (f16*)(wb);                                       // [3072][1024]
  f16*   Wproj_t = (f16*)(wb + (size_t)3072*1024*2);                 // [1024][1024]
  f16*   W1_t    = (f16*)(wb + (size_t)(3072+1024)*1024*2);          // [4096][1024]
  f16*   W2_t    = (f16*)(wb + (size_t)(3072+1024+4096)*1024*2);     // [1024][4096]

  dim3 blk(256), blk5(512);
  // ---- pack all weights to f16 B^T layouts (single fused launch)
  transpose_all<<<dim3(12288), blk, 0, stream>>>(Wq, Wk, Wv, Wproj, W1, W2,
                                                 Wqkv_t, Wproj_t, W1_t, W2_t);
  // ---- ln1
  ln_kernel<<<NTOK, blk, 0, stream>>>(x, g1, bt1, x1f, x1h);
  // ---- fused QKV gemm [8192,1024] x [1024,3072]   (BN=128: 768 wg = 3 full rounds)
  gemm8<0,128><<<dim3(32, 24), blk5, 0, stream>>>(x1h, Wqkv_t, 1024, nullptr, nullptr, nullptr, qb, kb, vb);
  // ---- attention (MFMA flash, balanced two-pass blocks, dbuf pipeline)
  attn_mfma<<<dim3(8, 64), blk, 0, stream>>>(qb, kb, vb, attnb);
  // ---- proj + bias + residual(x1) -> x2 (in place over x1f)  (256 wg = 1 round)
  gemm8<1,128><<<dim3(32, 8), blk5, 0, stream>>>(attnb, Wproj_t, 1024, bproj, x1f, x1f, nullptr, nullptr, nullptr);
  // ---- ln2
  ln_kernel<<<NTOK, blk, 0, stream>>>(x1f, g2, bt2, x3f, x3h);
  // ---- ffn1: relu(x3 @ W1 + b1)   (BN=256: 512 wg = 2 full rounds)
  gemm8<2,256><<<dim3(32, 16), blk5, 0, stream>>>(x3h, W1_t, 1024, b1, nullptr, nullptr, hbuf, nullptr, nullptr);
  // ---- ffn2: x3 + h @ W2 + b2 -> out   (256 wg = 1 round)
  gemm8<3,128><<<dim3(32, 8), blk5, 0, stream>>>(hbuf, W2_t, 4096, b2, x3f, out, nullptr, nullptr, nullptr);
}

// Round 9
// 472.040 us; speedup vs baseline: 1.3036x; 1.0500x over previous
//
#include <hip/hip_runtime.h>
#include <cstdint>

typedef _Float16 f16;
typedef __attribute__((ext_vector_type(8))) _Float16 f16x8;
typedef __attribute__((ext_vector_type(4))) _Float16 f16x4;
typedef __attribute__((ext_vector_type(2))) _Float16 f16x2;
typedef __attribute__((ext_vector_type(4))) float f32x4;
typedef __attribute__((ext_vector_type(16))) float f32x16;

#define D_MODEL 1024
#define T_SEQ   2048
#define NTOK    8192      // B*T
#define DFF     4096
#define DHEAD   64

struct alignas(16) H8 { f16 h[8]; };

// async global->LDS, 16B per lane. LDS dest must be wave-uniform base; HW adds lane*16.
__device__ __forceinline__ void load_lds16(const void* gp, void* lp) {
  __builtin_amdgcn_global_load_lds(
      (const __attribute__((address_space(1))) unsigned int*)(unsigned long long)(uintptr_t)gp,
      (__attribute__((address_space(3))) unsigned int*)(unsigned int)(uintptr_t)lp,
      16, 0, 0);
}

// raw phase barrier: no vmcnt(0) drain (unlike __syncthreads), but full
// compiler fence so LDS reads/writes can't migrate across phases.
__device__ __forceinline__ void phase_bar() {
  asm volatile("" ::: "memory");
  __builtin_amdgcn_sched_barrier(0);
  __builtin_amdgcn_s_barrier();
  __builtin_amdgcn_sched_barrier(0);
  asm volatile("" ::: "memory");
}

__device__ __forceinline__ void wait_vm2() {
  asm volatile("s_waitcnt vmcnt(2)" ::: "memory");
  __builtin_amdgcn_sched_barrier(0);
}
__device__ __forceinline__ void wait_vm0() {
  asm volatile("s_waitcnt vmcnt(0)" ::: "memory");
  __builtin_amdgcn_sched_barrier(0);
}

// ---------------------------------------------------------------------------
// All six weight transposes fused into ONE kernel (was 6 launches):
// out[c][r] = (f16) in[r][c]. 12288 blocks x one 32x32 tile each.
// ---------------------------------------------------------------------------
__global__ __launch_bounds__(256) void transpose_all(
    const float* __restrict__ Wq, const float* __restrict__ Wk,
    const float* __restrict__ Wv, const float* __restrict__ Wproj,
    const float* __restrict__ W1, const float* __restrict__ W2,
    f16* __restrict__ Wqkv_t, f16* __restrict__ Wproj_t,
    f16* __restrict__ W1_t, f16* __restrict__ W2_t)
{
  __shared__ float tile[32][33];
  int b = blockIdx.x;
  const float* in; f16* out; int rows, cols, r0, c0;
  if (b < 3072) {
    int j = b >> 10;                       // 0,1,2 -> q,k,v
    int local = b & 1023;
    int slice = local >> 6;                // 64 tiles per [1024][64] slice
    int tl = local & 63;
    in  = (j == 0 ? Wq : (j == 1 ? Wk : Wv)) + (size_t)slice * 65536;
    out = Wqkv_t + (size_t)j * 1024 * 1024 + (size_t)slice * 65536;
    rows = 1024; cols = 64;
    r0 = (tl & 31) * 32; c0 = (tl >> 5) * 32;
  } else if (b < 4096) {
    int tl = b - 3072;
    in = Wproj; out = Wproj_t; rows = 1024; cols = 1024;
    r0 = (tl & 31) * 32; c0 = (tl >> 5) * 32;
  } else if (b < 8192) {
    int tl = b - 4096;
    in = W1; out = W1_t; rows = 1024; cols = 4096;
    r0 = (tl & 31) * 32; c0 = (tl >> 5) * 32;
  } else {
    int tl = b - 8192;
    in = W2; out = W2_t; rows = 4096; cols = 1024;
    r0 = (tl & 127) * 32; c0 = (tl >> 7) * 32;
  }
  int tx = threadIdx.x & 31, ty = threadIdx.x >> 5;   // 32 x 8
  #pragma unroll
  for (int i = 0; i < 4; ++i)
    tile[ty + i*8][tx] = in[(size_t)(r0 + ty + i*8)*cols + c0 + tx];
  __syncthreads();
  #pragma unroll
  for (int i = 0; i < 4; ++i)
    out[(size_t)(c0 + ty + i*8)*rows + r0 + tx] = (f16)tile[tx][ty + i*8];
}

// row-wise layernorm over 1024; writes fp32 (residual path) + f16 (GEMM input)
__global__ __launch_bounds__(256) void ln_kernel(
    const float* __restrict__ x, const float* __restrict__ g, const float* __restrict__ b,
    float* __restrict__ outf, f16* __restrict__ outh)
{
  int row = blockIdx.x;
  const float* xr = x + (size_t)row * D_MODEL;
  int tid = threadIdx.x;
  float v[4];
  float s = 0.f;
  #pragma unroll
  for (int i = 0; i < 4; ++i) { v[i] = xr[tid + i*256]; s += v[i]; }
  #pragma unroll
  for (int off = 32; off > 0; off >>= 1) s += __shfl_down(s, off, 64);
  __shared__ float red1[4], red2[4];
  if ((tid & 63) == 0) red1[tid >> 6] = s;
  __syncthreads();
  float mean = (red1[0] + red1[1] + red1[2] + red1[3]) * (1.f / D_MODEL);
  float s2 = 0.f;
  #pragma unroll
  for (int i = 0; i < 4; ++i) { float d = v[i] - mean; s2 += d * d; }
  #pragma unroll
  for (int off = 32; off > 0; off >>= 1) s2 += __shfl_down(s2, off, 64);
  if ((tid & 63) == 0) red2[tid >> 6] = s2;
  __syncthreads();
  float var = (red2[0] + red2[1] + red2[2] + red2[3]) * (1.f / D_MODEL);
  float rstd = rsqrtf(var + 1e-5f);
  #pragma unroll
  for (int i = 0; i < 4; ++i) {
    int c = tid + i*256;
    float y = (v[i] - mean) * rstd * g[c] + b[c];
    outf[(size_t)row*D_MODEL + c] = y;
    outh[(size_t)row*D_MODEL + c] = (f16)y;
  }
}

// ---------------------------------------------------------------------------
// 256xBN phased GEMM (plain-HIP port of the 8-phase template, T2+T3+T4+T5).
// MODE 0: scatter q/k/v (q scaled log2e/32) -> o0,o1,o2 [BH][T][64] f16
// MODE 1: outf = acc + bias[col] + resid[idx]            (proj, fp32)
// MODE 2: o0   = relu(acc + bias[col])                   (ffn1, f16, ld 4096)
// MODE 3: outf = acc + bias[col] + resid[idx]            (ffn2 -> d_out)
// ---------------------------------------------------------------------------

#define STAGE_H(gbase, h, ldst, k0)                                            \
  { _Pragma("unroll")                                                          \
    for (int j_ = 0; j_ < 2; ++j_) {                                           \
      int c_  = tid + j_*512;                                                  \
      int rr_ = c_ >> 3;                                                       \
      int cg_ = (c_ & 7) ^ (rr_ & 7);                                          \
      load_lds16((gbase) + (size_t)((h)*128 + rr_) * K + (k0) + cg_*8,         \
                 (ldst) + (h)*128*64 + (size_t)(c_ & ~63) * 8);                \
    } }

#define LDS_A(bsel, mp)                                                        \
  { _Pragma("unroll")                                                          \
    for (int i_ = 0; i_ < 2; ++i_)                                             \
      _Pragma("unroll")                                                        \
      for (int ks_ = 0; ks_ < 4; ++ks_)                                        \
        fa[i_][ks_] = *(const f16x8*)(&As[bsel][                               \
            (wm + ((mp)*2 + i_)*32 + rl)*64 + (((ks_*2 + hl) ^ sw)*8)]); }

#define LDS_B(bsel, ni, fb)                                                    \
  { _Pragma("unroll")                                                          \
    for (int ks_ = 0; ks_ < 4; ++ks_)                                          \
      fb[ks_] = *(const f16x8*)(&Bs[bsel][                                     \
          (wn + (ni)*32 + rl)*64 + (((ks_*2 + hl) ^ sw)*8)]); }

#define MFMA8(mp, ni, fb)                                                      \
  { __builtin_amdgcn_s_setprio(1);                                             \
    _Pragma("unroll")                                                          \
    for (int ks_ = 0; ks_ < 4; ++ks_) {                                        \
      acc[(mp)*2+0][ni] = __builtin_amdgcn_mfma_f32_32x32x16_f16(              \
          fa[0][ks_], fb[ks_], acc[(mp)*2+0][ni], 0, 0, 0);                    \
      acc[(mp)*2+1][ni] = __builtin_amdgcn_mfma_f32_32x32x16_f16(              \
          fa[1][ks_], fb[ks_], acc[(mp)*2+1][ni], 0, 0, 0);                    \
    }                                                                          \
    __builtin_amdgcn_s_setprio(0); }

template<int MODE, int BN>
__global__ __launch_bounds__(512, 2) void gemm8(
    const f16* __restrict__ A, const f16* __restrict__ BT, int K,
    const float* __restrict__ bias, const float* __restrict__ resid,
    float* __restrict__ outf, f16* __restrict__ o0, f16* __restrict__ o1, f16* __restrict__ o2)
{
  constexpr int BM  = 256;
  constexpr int NWN = BN / 64;            // waves along N (4 or 2)
  constexpr int MI  = (BM / (8 / NWN)) / 32;  // mi frags per wave (4 or 2)

  __shared__ __align__(16) f16 As[2][BM * 64];
  __shared__ __align__(16) f16 Bs[2][BN * 64];

  int tid  = threadIdx.x;
  int lane = tid & 63;
  int wave = tid >> 6;
  int rl = lane & 31, hl = lane >> 5;
  int sw = rl & 7;
  int wmi = wave / NWN, wni = wave % NWN;
  int wm = wmi * (MI * 32), wn = wni * 64;

  // XCD swizzle, A-panel-major (r6 lesson: ffn2's 67MB A was streamed once
  // per column-block -> 282MB FETCH). Each XCD gets a contiguous sid chunk;
  // within it, consecutive sids share bx (same A panel) and span all by.
  int gx  = gridDim.x;
  int gy  = gridDim.y;
  int nwg = gx * gy;
  int lin = blockIdx.x + gx * blockIdx.y;
  int sid = (nwg & 7) == 0 ? ((lin & 7) * (nwg >> 3) + (lin >> 3)) : lin;
  int bx  = sid / gy, by = sid % gy;

  size_t row0 = (size_t)bx * BM, col0 = (size_t)by * BN;
  const f16* a_base = A  + row0 * K;
  const f16* b_base = BT + col0 * K;
  int NT = K >> 6;

  f32x16 acc[MI][2];
  #pragma unroll
  for (int i = 0; i < MI; ++i)
    #pragma unroll
    for (int j = 0; j < 2; ++j)
      acc[i][j] = (f32x16)(0.f);

  f16x8 fa[2][4], fb0[4], fb1[4];

  if constexpr (BN == 256) {
    STAGE_H(a_base, 0, &As[0][0], 0);
    STAGE_H(a_base, 1, &As[0][0], 0);
    STAGE_H(b_base, 0, &Bs[0][0], 0);
    STAGE_H(b_base, 1, &Bs[0][0], 0);
    if (NT > 1) { STAGE_H(a_base, 0, &As[1][0], 64); wait_vm2(); }
    else        { wait_vm0(); }
    phase_bar();

    for (int t = 0; t < NT; ++t) {
      int cur = t & 1, nxt = cur ^ 1;
      int k1 = (t + 1) << 6, k2 = (t + 2) << 6;
      bool s1 = (t + 1) < NT, s2 = (t + 2) < NT;
      LDS_A(cur, 0); LDS_B(cur, 0, fb0);
      if (s1) STAGE_H(a_base, 1, &As[nxt][0], k1);
      phase_bar();
      MFMA8(0, 0, fb0);
      phase_bar();
      LDS_B(cur, 1, fb1);
      if (s1) STAGE_H(b_base, 0, &Bs[nxt][0], k1);
      phase_bar();
      MFMA8(0, 1, fb1);
      phase_bar();
      LDS_A(cur, 1);
      if (s1) STAGE_H(b_base, 1, &Bs[nxt][0], k1);
      phase_bar();
      MFMA8(1, 0, fb0);
      phase_bar();
      if (s2) STAGE_H(a_base, 0, &As[cur][0], k2);
      phase_bar();
      MFMA8(1, 1, fb1);
      if (s2) wait_vm2(); else wait_vm0();
      phase_bar();
    }
  } else {
    STAGE_H(a_base, 0, &As[0][0], 0);
    STAGE_H(a_base, 1, &As[0][0], 0);
    STAGE_H(b_base, 0, &Bs[0][0], 0);
    if (NT > 1) { STAGE_H(a_base, 0, &As[1][0], 64); wait_vm2(); }
    else        { wait_vm0(); }
    phase_bar();

    for (int t = 0; t < NT; t += 2) {
      int k1 = (t + 1) << 6, k2 = (t + 2) << 6, k3 = (t + 3) << 6;
      bool s1 = (t + 1) < NT, s2 = (t + 2) < NT, s3 = (t + 3) < NT;
      LDS_A(0, 0); LDS_B(0, 0, fb0);
      if (s1) { STAGE_H(a_base, 1, &As[1][0], k1); STAGE_H(b_base, 0, &Bs[1][0], k1); }
      phase_bar();
      MFMA8(0, 0, fb0);
      phase_bar();
      LDS_B(0, 1, fb1);
      if (s2) STAGE_H(a_base, 0, &As[0][0], k2);
      phase_bar();
      MFMA8(0, 1, fb1);
      if (s2) wait_vm2(); else wait_vm0();
      phase_bar();
      if (!s1) break;
      LDS_A(1, 0); LDS_B(1, 0, fb0);
      if (s2) { STAGE_H(a_base, 1, &As[0][0], k2); STAGE_H(b_base, 0, &Bs[0][0], k2); }
      phase_bar();
      MFMA8(0, 0, fb0);
      phase_bar();
      LDS_B(1, 1, fb1);
      if (s3) STAGE_H(a_base, 0, &As[1][0], k3);
      phase_bar();
      MFMA8(0, 1, fb1);
      if (s3) wait_vm2(); else wait_vm0();
      phase_bar();
    }
  }

  // epilogue: 32x32 C layout (m74/m101): col=lane&31, row=(reg&3)+8*(reg>>2)+4*(lane>>5)
  int rb = hl * 4;
  #pragma unroll
  for (int mi = 0; mi < MI; ++mi) {
    #pragma unroll
    for (int ni = 0; ni < 2; ++ni) {
      #pragma unroll
      for (int r = 0; r < 16; ++r) {
        size_t grow = row0 + wm + mi*32 + rb + (r & 3) + 8 * (r >> 2);
        size_t gcol = col0 + wn + ni*32 + rl;
        float v = acc[mi][ni][r];
        if constexpr (MODE == 0) {
          int sel = (int)(gcol >> 10);
          int hh  = ((int)gcol >> 6) & 15;
          int dd  = (int)gcol & 63;
          f16* dst = (sel == 0) ? o0 : ((sel == 1) ? o1 : o2);
          if (sel == 0) v *= 0.045084229f;   // (1/32) * log2(e): exp2-domain scores
          size_t bh = (grow >> 11) * 16 + hh;
          dst[(bh * T_SEQ + (grow & 2047)) * DHEAD + dd] = (f16)v;
        } else if constexpr (MODE == 1 || MODE == 3) {
          size_t idx = grow * D_MODEL + gcol;
          outf[idx] = v + bias[gcol] + resid[idx];
        } else {  // MODE 2
          float t = v + bias[gcol];
          o0[grow * (size_t)DFF + gcol] = (f16)(t > 0.f ? t : 0.f);
        }
      }
    }
  }
}

// MFMA flash attention, S^T formulation + fixed-max softmax.
// Balanced two-pass blocks (512 blocks, uniform 34 k-tiles), dbuf K/V with
// depth-1 register prefetch, single barrier/tile, setprio on MFMA clusters.
// r8/r9 changes:
//  (1) grid transposed to (64 bh, 8 bx): same-bh blocks get lin%8 == bh%8 ->
//      SAME XCD, so one head's 512KB K/V lives in one L2 (8 heads = 4MB/XCD).
//      r7 FETCH was 147MB vs 50MB of inputs: same-bh blocks on 8 different
//      XCDs each re-fetched K/V from HBM.
//  (2) lsum computed by MFMA instead of VALU: Vt has 16 extra d-rows
//      (row 64 = 1.0, 65..79 = 0, written once); one extra mfma per (kj,mb)
//      accumulates row-sums into o4 -> deletes 32 serial v_add per lane/tile
//      and the end-of-pass shuffle reduce (VALU was the busiest pipe, 45%).
//  (3) P->f16 via v_cvt_pkrtz (2 f32 per instr); bit_cast fixes the
//      __fp16-vector vs _Float16-vector type spelling (r8 compile error).
__global__ __launch_bounds__(256) void attn_mfma(
    const f16* __restrict__ qb, const f16* __restrict__ kb,
    const f16* __restrict__ vb, f16* __restrict__ attnb)
{
  constexpr int KT  = 64;
  constexpr int LDK = 72;                        // padded f16 stride (K, Vt, Pt)
  __shared__ __align__(16) f16 Kl[2][KT * LDK];        // [buf][key][d]    18.4 KB
  __shared__ __align__(16) f16 Vt[2][(DHEAD+16) * LDK];// [buf][d][key]    23.0 KB
  __shared__ __align__(16) f16 Pt[4 * 32 * LDK];       // per-wave [q][key]18.4 KB

  int tid  = threadIdx.x;
  int lane = tid & 63, wave = tid >> 6;
  int n    = lane & 15, quad = lane >> 4;
  int quad4 = quad * 4;
  int bh   = blockIdx.x;                         // (1) bh on grid.x -> XCD affinity
  int bxq  = blockIdx.y;

  const f16* qg = qb + (size_t)bh * T_SEQ * DHEAD;
  const f16* kg = kb + (size_t)bh * T_SEQ * DHEAD;
  const f16* vg = vb + (size_t)bh * T_SEQ * DHEAD;
  f16* Ptw = Pt + wave * 32 * LDK;
  size_t orow = (size_t)(bh >> 4) * T_SEQ;
  int hcol = (bh & 15) * DHEAD;

  // staging geometry (constant per thread)
  int skey0 = tid >> 3,  sdq = tid & 7;          // K halves: keys skey0, skey0+32
  int kp = tid & 31, dblk = tid >> 5;            // V: keys 2kp,2kp+1; d = dblk*8+e

  // (2) ones/zero rows 64..79 of both Vt buffers, written ONCE (V staging
  // only touches rows 0..63). row 64 = 1.0 -> MFMA computes row-sums of P.
  {
    int row = 64 + (tid >> 4);
    int colg = (tid & 15) * 4;
    f16 oneval = (f16)((tid >> 4) == 0 ? 1.0f : 0.0f);
    f16x4 fill = {oneval, oneval, oneval, oneval};
    *(f16x4*)(&Vt[0][0] + row * LDK + colg) = fill;
    *(f16x4*)(&Vt[1][0] + row * LDK + colg) = fill;
  }

  #pragma unroll
  for (int pass = 0; pass < 2; ++pass) {
    int qi = pass == 0 ? (15 - bxq) : bxq;       // balanced pairing
    int qw = qi * 128 + wave * 32;               // this wave's first q row

    // Q fragments (B-operand): lane n holds Q[q=qw+ni*16+n][d=quad*8+j]
    f16x8 qfrag[2][2];
    #pragma unroll
    for (int ni = 0; ni < 2; ++ni)
      #pragma unroll
      for (int kj = 0; kj < 2; ++kj)
        qfrag[ni][kj] = *(const f16x8*)(qg + (size_t)(qw + ni*16 + n)*DHEAD + kj*32 + quad*8);

    f32x4 o[2][4];
    f32x4 o4[2];                                 // (2) row-sum accumulators (d=64 col)
    #pragma unroll
    for (int mb = 0; mb < 2; ++mb) {
      #pragma unroll
      for (int di = 0; di < 4; ++di) o[mb][di] = f32x4{0.f,0.f,0.f,0.f};
      o4[mb] = f32x4{0.f,0.f,0.f,0.f};
    }

    int ntiles = 2 * qi + 2;

    // ---- pipeline prologue: tile 0 -> regs -> buf0; issue tile 1 -> regs.
    uint4 kpre0 = *(const uint4*)(kg + (size_t)skey0 * DHEAD + sdq * 8);
    uint4 kpre1 = *(const uint4*)(kg + (size_t)(skey0 + 32) * DHEAD + sdq * 8);
    H8 vpa = *(const H8*)(vg + (size_t)(2*kp) * DHEAD + dblk * 8);
    H8 vpb = *(const H8*)(vg + (size_t)(2*kp) * DHEAD + DHEAD + dblk * 8);
    *(uint4*)(&Kl[0][0] + skey0 * LDK + sdq * 8) = kpre0;
    *(uint4*)(&Kl[0][0] + (skey0 + 32) * LDK + sdq * 8) = kpre1;
    #pragma unroll
    for (int e = 0; e < 8; ++e) {
      f16x2 pk2; pk2[0] = vpa.h[e]; pk2[1] = vpb.h[e];
      *(f16x2*)(&Vt[0][0] + (dblk*8 + e) * LDK + 2*kp) = pk2;
    }
    if (ntiles > 1) {
      kpre0 = *(const uint4*)(kg + (size_t)(KT + skey0) * DHEAD + sdq * 8);
      kpre1 = *(const uint4*)(kg + (size_t)(KT + skey0 + 32) * DHEAD + sdq * 8);
      vpa = *(const H8*)(vg + (size_t)(KT + 2*kp) * DHEAD + dblk * 8);
      vpb = *(const H8*)(vg + (size_t)(KT + 2*kp) * DHEAD + DHEAD + dblk * 8);
    }
    __syncthreads();

    for (int kt = 0; kt < ntiles; ++kt) {
      int kt0 = kt * KT;
      // stage tile kt+1 (already in regs) into the other buffer; issue kt+2
      if (kt + 1 < ntiles) {
        f16* Kn = &Kl[(kt + 1) & 1][0];
        f16* Vn = &Vt[(kt + 1) & 1][0];
        *(uint4*)(Kn + skey0 * LDK + sdq * 8) = kpre0;
        *(uint4*)(Kn + (skey0 + 32) * LDK + sdq * 8) = kpre1;
        #pragma unroll
        for (int e = 0; e < 8; ++e) {
          f16x2 pk2; pk2[0] = vpa.h[e]; pk2[1] = vpb.h[e];
          *(f16x2*)(Vn + (dblk*8 + e) * LDK + 2*kp) = pk2;
        }
        if (kt + 2 < ntiles) {
          int nt0 = kt0 + 2 * KT;
          kpre0 = *(const uint4*)(kg + (size_t)(nt0 + skey0) * DHEAD + sdq * 8);
          kpre1 = *(const uint4*)(kg + (size_t)(nt0 + skey0 + 32) * DHEAD + sdq * 8);
          vpa = *(const H8*)(vg + (size_t)(nt0 + 2*kp) * DHEAD + dblk * 8);
          vpb = *(const H8*)(vg + (size_t)(nt0 + 2*kp) * DHEAD + DHEAD + dblk * 8);
        }
      }

      if (kt0 <= qw + 31) {                      // not fully masked for this wave
        const f16* Kc = &Kl[kt & 1][0];
        const f16* Vc = &Vt[kt & 1][0];
        bool need_mask = (kt0 + KT - 1) > qw;    // diagonal tile

        // S^T = K Q^T : [64 key][32 q]; lane holds (key=mi*16+quad4+r, q=ni*16+n)
        f32x4 st[4][2];
        #pragma unroll
        for (int mi = 0; mi < 4; ++mi)
          #pragma unroll
          for (int ni = 0; ni < 2; ++ni) st[mi][ni] = f32x4{0.f,0.f,0.f,0.f};
        __builtin_amdgcn_s_setprio(1);
        #pragma unroll
        for (int kj = 0; kj < 2; ++kj) {
          #pragma unroll
          for (int mi = 0; mi < 4; ++mi) {
            f16x8 kf = *(const f16x8*)(Kc + (mi*16 + n) * LDK + kj*32 + quad*8);
            #pragma unroll
            for (int ni = 0; ni < 2; ++ni)
              st[mi][ni] = __builtin_amdgcn_mfma_f32_16x16x32_f16(kf, qfrag[ni][kj], st[mi][ni], 0, 0, 0);
          }
        }
        __builtin_amdgcn_s_setprio(0);

        // p = exp2(s'); pack via cvt_pkrtz; P^T -> LDS (b64, key-contiguous)
        #pragma unroll
        for (int ni = 0; ni < 2; ++ni) {
          #pragma unroll
          for (int mi = 0; mi < 4; ++mi) {
            float pv[4];
            #pragma unroll
            for (int r = 0; r < 4; ++r) {
              float sv = st[mi][ni][r];
              if (need_mask) {
                int key = kt0 + mi*16 + quad4 + r;
                int qq  = qw  + ni*16 + n;
                if (key > qq) sv = -1e30f;
              }
              pv[r] = __builtin_amdgcn_exp2f(sv);
            }
            f16x2 lo = __builtin_bit_cast(f16x2, __builtin_amdgcn_cvt_pkrtz(pv[0], pv[1]));
            f16x2 hi = __builtin_bit_cast(f16x2, __builtin_amdgcn_cvt_pkrtz(pv[2], pv[3]));
            f16x4 pk; pk[0] = lo[0]; pk[1] = lo[1]; pk[2] = hi[0]; pk[3] = hi[1];
            *(f16x4*)(Ptw + (ni*16 + n) * LDK + mi*16 + quad4) = pk;
          }
        }

        // O += P V (+ row-sum via ones-column): A-frag = Pt rows, B-frag = Vt rows
        __builtin_amdgcn_s_setprio(1);
        #pragma unroll
        for (int kj = 0; kj < 2; ++kj) {
          f16x8 pf[2];
          #pragma unroll
          for (int mb = 0; mb < 2; ++mb)
            pf[mb] = *(const f16x8*)(Ptw + (mb*16 + n) * LDK + kj*32 + quad*8);
          #pragma unroll
          for (int di = 0; di < 4; ++di) {
            f16x8 vf = *(const f16x8*)(Vc + (di*16 + n) * LDK + kj*32 + quad*8);
            #pragma unroll
            for (int mb = 0; mb < 2; ++mb)
              o[mb][di] = __builtin_amdgcn_mfma_f32_16x16x32_f16(pf[mb], vf, o[mb][di], 0, 0, 0);
          }
          f16x8 vfo = *(const f16x8*)(Vc + (64 + n) * LDK + kj*32 + quad*8);
          #pragma unroll
          for (int mb = 0; mb < 2; ++mb)
            o4[mb] = __builtin_amdgcn_mfma_f32_16x16x32_f16(pf[mb], vfo, o4[mb], 0, 0, 0);
        }
        __builtin_amdgcn_s_setprio(0);
      }
      __syncthreads();                           // single barrier per tile
    }

    // epilogue: lane holds (q=mb*16+quad4+r, d=di*16+n); row-sum for q sits
    // in o4[mb][r] at lane quad*16 (n=0 of that quad) -> one shfl broadcast.
    #pragma unroll
    for (int mb = 0; mb < 2; ++mb) {
      #pragma unroll
      for (int r = 0; r < 4; ++r) {
        float lv  = __shfl(o4[mb][r], quad * 16, 64);
        float inv = 1.f / lv;
        int t = qw + mb*16 + quad4 + r;
        #pragma unroll
        for (int di = 0; di < 4; ++di)
          attnb[(orow + t) * D_MODEL + hcol + di*16 + n] = (f16)(o[mb][di][r] * inv);
      }
    }
  }
}

extern "C" void kernel_launch(void* const* d_in, const int* in_sizes, int n_in,
                              void* d_out, int out_size, void* d_ws, size_t ws_size,
                              hipStream_t stream)
{
  const float* x     = (const float*)d_in[0];
  const float* Wq    = (const float*)d_in[1];
  const float* Wk    = (const float*)d_in[2];
  const float* Wv    = (const float*)d_in[3];
  const float* Wproj = (const float*)d_in[4];
  const float* bproj = (const float*)d_in[5];
  const float* W1    = (const float*)d_in[6];
  const float* b1    = (const float*)d_in[7];
  const float* W2    = (const float*)d_in[8];
  const float* b2    = (const float*)d_in[9];
  const float* g1    = (const float*)d_in[10];
  const float* bt1   = (const float*)d_in[11];
  const float* g2    = (const float*)d_in[12];
  const float* bt2   = (const float*)d_in[13];
  float* out = (float*)d_out;
  (void)in_sizes; (void)n_in; (void)out_size; (void)ws_size;

  char* ws = (char*)d_ws;
  const size_t SZ_H16 = (size_t)NTOK * D_MODEL * 2;  // 16.78 MB
  const size_t SZ_F32 = (size_t)NTOK * D_MODEL * 4;  // 33.55 MB
  f16*   qb      = (f16*)(ws + 0);
  f16*   kb      = (f16*)(ws + 1 * SZ_H16);
  f16*   vb      = (f16*)(ws + 2 * SZ_H16);
  f16*   attnb   = (f16*)(ws + 3 * SZ_H16);
  f16*   hbuf    = (f16*)(ws + 0);                   // reuses q/k/v/attn after proj (67.1MB)
  float* x1f     = (float*)(ws + 4 * SZ_H16);        // becomes x2 in-place at proj
  f16*   x1h     = (f16*)(ws + 4 * SZ_H16 + SZ_F32);
  float* x3f     = (float*)(ws + 5 * SZ_H16 + SZ_F32);
  f16*   x3h     = (f16*)(ws + 5 * SZ_H16 + 2 * SZ_F32);
  char*  wb      = ws + 6 * SZ_H16 + 2 * SZ_F32;
  f16*   Wqkv_t  = (f16*)(wb);                                       // [3072][1024]
  f16*   Wproj_t = (f16*)(wb + (size_t)3072*1024*2);                 // [1024][1024]
  f16*   W1_t    = (f16*)(wb + (size_t)(3072+1024)*1024*2);          // [4096][1024]
  f16*   W2_t    = (f16*)(wb + (size_t)(3072+1024+4096)*1024*2);     // [1024][4096]

  dim3 blk(256), blk5(512);
  // ---- pack all weights to f16 B^T layouts (single fused launch)
  transpose_all<<<dim3(12288), blk, 0, stream>>>(Wq, Wk, Wv, Wproj, W1, W2,
                                                 Wqkv_t, Wproj_t, W1_t, W2_t);
  // ---- ln1
  ln_kernel<<<NTOK, blk, 0, stream>>>(x, g1, bt1, x1f, x1h);
  // ---- fused QKV gemm [8192,1024] x [1024,3072]   (BN=128: 768 wg = 3 full rounds)
  gemm8<0,128><<<dim3(32, 24), blk5, 0, stream>>>(x1h, Wqkv_t, 1024, nullptr, nullptr, nullptr, qb, kb, vb);
  // ---- attention (grid (bh, bx): same-head blocks share an XCD/L2)
  attn_mfma<<<dim3(64, 8), blk, 0, stream>>>(qb, kb, vb, attnb);
  // ---- proj + bias + residual(x1) -> x2 (in place over x1f)  (256 wg = 1 round)
  gemm8<1,128><<<dim3(32, 8), blk5, 0, stream>>>(attnb, Wproj_t, 1024, bproj, x1f, x1f, nullptr, nullptr, nullptr);
  // ---- ln2
  ln_kernel<<<NTOK, blk, 0, stream>>>(x1f, g2, bt2, x3f, x3h);
  // ---- ffn1: relu(x3 @ W1 + b1)   (BN=256: 512 wg = 2 full rounds)
  gemm8<2,256><<<dim3(32, 16), blk5, 0, stream>>>(x3h, W1_t, 1024, b1, nullptr, nullptr, hbuf, nullptr, nullptr);
  // ---- ffn2: x3 + h @ W2 + b2 -> out   (256 wg = 1 round)
  gemm8<3,128><<<dim3(32, 8), blk5, 0, stream>>>(hbuf, W2_t, 4096, b2, x3f, out, nullptr, nullptr, nullptr);
}